// Round 10
// baseline (163.929 us; speedup 1.0000x reference)
//
#include <hip/hip_runtime.h>

#define BB 16
#define CC 256
#define NN 4096
#define CN (CC*NN)
#define GG 8
#define EPSF 1e-8f
#define NT 64      // n-tile per block
#define STR 68     // padded LDS row stride (words); 16B-aligned rows

// ---------------- transpose conv_w -> wT[c][d] ----------------------------------------------
__global__ __launch_bounds__(256) void k_wt(const float* __restrict__ conv_w,
                                            float* __restrict__ wT) {
  int o = blockIdx.x * 256 + threadIdx.x;  // 16384
  int d = o >> 8, c = o & 255;
  wT[c * 64 + d] = conv_w[d * 256 + c];
}

// ---------------- prep: x passthrough + xnorm partials + conv/relu/pool --------------------
// grid: 16 b x 64 n-tiles(64). block 512 = 8 waves, 2 blocks/CU (71.7KB LDS).
// Conv: lane = d (64), wave owns 8 n. Weights = PER-LANE GLOBAL loads (vmcnt);
// x = UNIFORM LDS broadcasts (lgkmcnt) -> separate counters, both pipeline.
__global__ __launch_bounds__(512) void k_prep(const float* __restrict__ x,
                                              const float* __restrict__ wT,
                                              const float* __restrict__ conv_b,
                                              float* __restrict__ xout,
                                              float* __restrict__ xnp,
                                              float* __restrict__ pooledpart) {
  const int b = blockIdx.x >> 6;
  const int chunk = blockIdx.x & 63;
  const int t = threadIdx.x;
  const int lane = t & 63, wv = t >> 6;  // wv 0..7
  __shared__ float xs[256 * STR];  // 69632 B
  __shared__ float pool[8 * 64];   // 2048 B

  // stage x tile: rows r = k*32 + (t>>4), float4-col j = t&15
  const float* xb = x + (size_t)b * CN + chunk * NT;
  const int r0 = t >> 4, j = t & 15;
  float4 v[8];
  float sq[8];
#pragma unroll
  for (int k = 0; k < 8; ++k)
    v[k] = *(const float4*)(xb + (size_t)(k * 32 + r0) * NN + j * 4);
#pragma unroll
  for (int k = 0; k < 8; ++k) {
    *(float4*)&xs[(k * 32 + r0) * STR + j * 4] = v[k];
    sq[k] = v[k].x * v[k].x + v[k].y * v[k].y + v[k].z * v[k].z + v[k].w * v[k].w;
  }
  float* xo = xout + (size_t)b * CN + chunk * NT;
#pragma unroll
  for (int k = 0; k < 8; ++k)
    *(float4*)(xo + (size_t)(k * 32 + r0) * NN + j * 4) = v[k];
#pragma unroll
  for (int k = 0; k < 8; ++k) {
    float s = sq[k];
    s += __shfl_xor(s, 1, 64); s += __shfl_xor(s, 2, 64);
    s += __shfl_xor(s, 4, 64); s += __shfl_xor(s, 8, 64);
    sq[k] = s;
  }
  if ((t & 15) == 0) {
    float* xp = xnp + ((size_t)b * 64 + chunk) * 256 + r0;
#pragma unroll
    for (int k = 0; k < 8; ++k) xp[k * 32] = sq[k];
  }
  const float bias = conv_b[lane];  // per-lane, coalesced
  __syncthreads();

  // conv: acc[i] = sum_c wT[c][lane] * xs[c][n0+i]
  const int n0 = __builtin_amdgcn_readfirstlane(wv) * 8;
  float acc[8];
#pragma unroll
  for (int i = 0; i < 8; ++i) acc[i] = 0.f;
  const float* wp = wT + lane;
#pragma unroll 4
  for (int c = 0; c < 256; ++c) {
    float w = wp[c * 64];  // per-lane global b32, coalesced, L1/L2-hot
    float4 xa = *(const float4*)&xs[c * STR + n0];      // uniform broadcast
    float4 xb2 = *(const float4*)&xs[c * STR + n0 + 4];
    acc[0] = fmaf(w, xa.x, acc[0]);
    acc[1] = fmaf(w, xa.y, acc[1]);
    acc[2] = fmaf(w, xa.z, acc[2]);
    acc[3] = fmaf(w, xa.w, acc[3]);
    acc[4] = fmaf(w, xb2.x, acc[4]);
    acc[5] = fmaf(w, xb2.y, acc[5]);
    acc[6] = fmaf(w, xb2.z, acc[6]);
    acc[7] = fmaf(w, xb2.w, acc[7]);
  }
  float p = 0.f;
#pragma unroll
  for (int i = 0; i < 8; ++i) p += fmaxf(acc[i] + bias, 0.f);
  pool[wv * 64 + lane] = p;
  __syncthreads();
  if (t < 64) {
    float s = 0.f;
#pragma unroll
    for (int w = 0; w < 8; ++w) s += pool[w * 64 + t];
    pooledpart[((size_t)b * 64 + chunk) * 64 + t] = s;
  }
}

// ---------------- pooled-reduce + logits + log(ga) + softmax -> wg --------------------------
__global__ __launch_bounds__(256) void k_logits(const float* __restrict__ pooledpart,
                                                const float* __restrict__ lin_w,
                                                const float* __restrict__ lin_b,
                                                const float* __restrict__ ga,
                                                float* __restrict__ logits,
                                                float* __restrict__ wg) {
  const int b = blockIdx.x, t = threadIdx.x;
  __shared__ float ps2[4][64];
  __shared__ float ps[64];
  {
    const int d = t & 63, q = t >> 6;
    float s = 0.f;
#pragma unroll
    for (int k = 0; k < 16; ++k)
      s += pooledpart[((size_t)b * 64 + q * 16 + k) * 64 + d];
    ps2[q][d] = s;
  }
  __syncthreads();
  if (t < 64) ps[t] = (ps2[0][t] + ps2[1][t] + ps2[2][t] + ps2[3][t]) * (1.f / 4096.f);
  __syncthreads();
  const int c = t;
  float out[8];
#pragma unroll
  for (int g = 0; g < 8; ++g) {
    const float4* wr = (const float4*)(lin_w + ((size_t)c * 8 + g) * 64);
    float s = 0.f;
#pragma unroll
    for (int k4 = 0; k4 < 16; ++k4) {
      float4 wv = wr[k4];
      s += wv.x * ps[k4 * 4] + wv.y * ps[k4 * 4 + 1] + wv.z * ps[k4 * 4 + 2] +
           wv.w * ps[k4 * 4 + 3];
    }
    out[g] = s + lin_b[c * 8 + g] + logf(ga[((size_t)b * 256 + c) * 8 + g] + EPSF);
  }
  float* lp = logits + ((size_t)b * 256 + c) * 8;
  *(float4*)lp = make_float4(out[0], out[1], out[2], out[3]);
  *(float4*)(lp + 4) = make_float4(out[4], out[5], out[6], out[7]);
  float m = out[0];
#pragma unroll
  for (int g = 1; g < 8; ++g) m = fmaxf(m, out[g]);
  float sum = 0.f;
#pragma unroll
  for (int g = 0; g < 8; ++g) { out[g] = __expf(out[g] - m); sum += out[g]; }
  float r = 1.f / sum;
  float4* op = (float4*)(wg + ((size_t)b * 256 + c) * 8);
  op[0] = make_float4(out[0] * r, out[1] * r, out[2] * r, out[3] * r);
  op[1] = make_float4(out[4] * r, out[5] * r, out[6] * r, out[7] * r);
}

// ---------------- fused routing iteration: s-tile + sim partials ----------------------------
// grid: 16 b x 64 n-tiles(64). block 512 = 8 waves. LDS 80000B -> 2 blocks/CU.
// wg staged in LDS (all-LDS phase 1, in-order lgkmcnt pipelining; no s_load mixing).
__global__ __launch_bounds__(512) void k_route(const float* __restrict__ x,
                                               const float* __restrict__ wg,
                                               float* __restrict__ spart2,
                                               float* __restrict__ simpart) {
  const int b = blockIdx.x >> 6;
  const int chunk = blockIdx.x & 63;
  const int t = threadIdx.x;
  const int lane = t & 63, wv = t >> 6;
  __shared__ float xs[256 * STR];  // 69632 B (reused as pool2 in merge)
  __shared__ float st[8 * STR];    // 2176 B  s tile
  __shared__ float wls[2048];      // 8192 B  wg stage; reused as pool1[4][8][64]

  // stage x tile + wg
  const float* xb = x + (size_t)b * CN + chunk * NT;
  const int r0 = t >> 4, j = t & 15;
#pragma unroll
  for (int k = 0; k < 8; ++k) {
    float4 v = *(const float4*)(xb + (size_t)(k * 32 + r0) * NN + j * 4);
    *(float4*)&xs[(k * 32 + r0) * STR + j * 4] = v;
  }
  *(float4*)&wls[t * 4] = *(const float4*)(wg + (size_t)b * 2048 + t * 4);
  __syncthreads();

  // ---- phase 1 (waves 0..3): s partial over c-quarter; lane = n ----
  const int cq = __builtin_amdgcn_readfirstlane(wv);
  float sacc[8];
#pragma unroll
  for (int g = 0; g < 8; ++g) sacc[g] = 0.f;
  if (cq < 4) {
    const int c0 = cq * 64;
#pragma unroll 4
    for (int cc = 0; cc < 64; ++cc) {
      float xv = xs[(c0 + cc) * STR + lane];
      float4 wa = *(const float4*)&wls[(c0 + cc) * 8];
      float4 wb = *(const float4*)&wls[(c0 + cc) * 8 + 4];
      sacc[0] = fmaf(wa.x, xv, sacc[0]);
      sacc[1] = fmaf(wa.y, xv, sacc[1]);
      sacc[2] = fmaf(wa.z, xv, sacc[2]);
      sacc[3] = fmaf(wa.w, xv, sacc[3]);
      sacc[4] = fmaf(wb.x, xv, sacc[4]);
      sacc[5] = fmaf(wb.y, xv, sacc[5]);
      sacc[6] = fmaf(wb.z, xv, sacc[6]);
      sacc[7] = fmaf(wb.w, xv, sacc[7]);
    }
  }
  __syncthreads();  // wls reads done
  if (cq < 4) {
#pragma unroll
    for (int g = 0; g < 8; ++g) wls[(cq * 8 + g) * 64 + lane] = sacc[g];  // pool1
  }
  __syncthreads();
  // finalize st + spart2: wave = g, lane = n
  {
    const int g = wv, n = lane;
    float vv = wls[(0 * 8 + g) * 64 + n] + wls[(1 * 8 + g) * 64 + n] +
               wls[(2 * 8 + g) * 64 + n] + wls[(3 * 8 + g) * 64 + n];
    st[g * STR + n] = vv;
    float s2 = vv * vv;
#pragma unroll
    for (int off = 1; off < 64; off <<= 1) s2 += __shfl_xor(s2, off, 64);
    if (n == 0) spart2[((size_t)b * 64 + chunk) * 8 + g] = s2;
  }
  __syncthreads();

  // ---- phase 2: sim partials. thread: co=t&31 (c=co+32k), nq=t>>5 (4 n each) ----
  const int co = t & 31;
  const int nq = t >> 5;  // 0..15
  const int n0 = nq * 4;
  float4 sv[8];
#pragma unroll
  for (int g = 0; g < 8; ++g) sv[g] = *(const float4*)&st[g * STR + n0];
  float acc[8][8];
#pragma unroll
  for (int k = 0; k < 8; ++k)
#pragma unroll
    for (int g = 0; g < 8; ++g) acc[k][g] = 0.f;
#pragma unroll
  for (int k = 0; k < 8; ++k) {
    const int c = co + 32 * k;
    float4 xa = *(const float4*)&xs[c * STR + n0];
#pragma unroll
    for (int g = 0; g < 8; ++g) {
      float a = acc[k][g];
      a = fmaf(xa.x, sv[g].x, a);
      a = fmaf(xa.y, sv[g].y, a);
      a = fmaf(xa.z, sv[g].z, a);
      a = fmaf(xa.w, sv[g].w, a);
      acc[k][g] = a;
    }
  }
  // combine nq pairs within wave (lanes l <-> l+32)
#pragma unroll
  for (int k = 0; k < 8; ++k)
#pragma unroll
    for (int g = 0; g < 8; ++g) acc[k][g] += __shfl_xor(acc[k][g], 32, 64);
  __syncthreads();  // xs reads done -> reuse as pool2[(k*8+g)*264 + w*33 + co]
  float* pool2 = xs;
  if (lane < 32) {
#pragma unroll
    for (int k = 0; k < 8; ++k)
#pragma unroll
      for (int g = 0; g < 8; ++g)
        pool2[(k * 8 + g) * 264 + wv * 33 + co] = acc[k][g];  // stride-1 in co: conflict-free
  }
  __syncthreads();
  // merge over 8 waves: thread -> (co2, kk, g-half)
  {
    const int co2 = t & 31, kk = (t >> 5) & 7, half = t >> 8;
    float rr[4];
#pragma unroll
    for (int gg = 0; gg < 4; ++gg) {
      const int g = half * 4 + gg;
      float s = 0.f;
#pragma unroll
      for (int w = 0; w < 8; ++w) s += pool2[(kk * 8 + g) * 264 + w * 33 + co2];
      rr[gg] = s;
    }
    const int c = co2 + 32 * kk;
    *(float4*)(simpart + (((size_t)b * 64 + chunk) * 256 + c) * 8 + half * 4) =
        make_float4(rr[0], rr[1], rr[2], rr[3]);
  }
}

// ---------------- logits += sim/(xn*sn); !FINAL: softmax->wg (+xnorm); FINAL: ->d_out -------
template <int FINAL>
__global__ __launch_bounds__(256) void k_upd(const float* __restrict__ simpart,
                                             const float* __restrict__ xnp,
                                             const float* __restrict__ spart2,
                                             float* __restrict__ logits,
                                             float* __restrict__ xnorm,
                                             float* __restrict__ wg,
                                             float* __restrict__ outw) {
  const int b = blockIdx.x >> 4;
  const int c0 = (blockIdx.x & 15) * 16;
  const int t = threadIdx.x;
  __shared__ float simld[16][8];
  __shared__ float xnl[16];
  __shared__ float snr8[8];
  {
    const int pair = t >> 1, kh = t & 1;
    const int cl = pair >> 3, g = pair & 7;
    float sm = 0.f;
    const float* sp = simpart + (((size_t)b * 64 + kh * 32) * 256 + c0 + cl) * 8 + g;
#pragma unroll 8
    for (int k = 0; k < 32; ++k) sm += sp[(size_t)k * 2048];
    sm += __shfl_xor(sm, 1, 64);
    if (kh == 0) simld[cl][g] = sm;
  }
  {
    const int cl2 = t >> 4, kq = t & 15;
    if (!FINAL) {
      float p = 0.f;
#pragma unroll
      for (int j = 0; j < 4; ++j)
        p += xnp[((size_t)b * 64 + kq + 16 * j) * 256 + c0 + cl2];
      p += __shfl_xor(p, 1, 64); p += __shfl_xor(p, 2, 64);
      p += __shfl_xor(p, 4, 64); p += __shfl_xor(p, 8, 64);
      if (kq == 0) {
        float xn = fmaxf(sqrtf(p), EPSF);
        xnl[cl2] = xn;
        xnorm[b * 256 + c0 + cl2] = xn;
      }
    } else {
      if (kq == 0) xnl[cl2] = xnorm[b * 256 + c0 + cl2];
    }
  }
  if (t < 64) {
    const int g2 = t >> 3, kq = t & 7;
    float p = 0.f;
#pragma unroll
    for (int j = 0; j < 8; ++j) p += spart2[((size_t)b * 64 + kq + 8 * j) * 8 + g2];
    p += __shfl_xor(p, 1, 64); p += __shfl_xor(p, 2, 64); p += __shfl_xor(p, 4, 64);
    if (kq == 0) snr8[g2] = 1.f / fmaxf(sqrtf(p), EPSF);
  }
  __syncthreads();
  if (t < 16) {
    const int c = c0 + t;
    float* lp = logits + ((size_t)b * 256 + c) * 8;
    float4 l0 = *(const float4*)lp, l1 = *(const float4*)(lp + 4);
    float lg[8] = {l0.x, l0.y, l0.z, l0.w, l1.x, l1.y, l1.z, l1.w};
    const float xni = 1.f / xnl[t];
#pragma unroll
    for (int g = 0; g < 8; ++g) lg[g] += simld[t][g] * xni * snr8[g];
    if (!FINAL) {
      *(float4*)lp = make_float4(lg[0], lg[1], lg[2], lg[3]);
      *(float4*)(lp + 4) = make_float4(lg[4], lg[5], lg[6], lg[7]);
    }
    float m = lg[0];
#pragma unroll
    for (int g = 1; g < 8; ++g) m = fmaxf(m, lg[g]);
    float sum = 0.f;
#pragma unroll
    for (int g = 0; g < 8; ++g) { lg[g] = __expf(lg[g] - m); sum += lg[g]; }
    float r = 1.f / sum;
    float* dst = FINAL ? outw : wg;
    float4* op = (float4*)(dst + ((size_t)b * 256 + c) * 8);
    op[0] = make_float4(lg[0] * r, lg[1] * r, lg[2] * r, lg[3] * r);
    op[1] = make_float4(lg[4] * r, lg[5] * r, lg[6] * r, lg[7] * r);
  }
}

extern "C" void kernel_launch(void* const* d_in, const int* in_sizes, int n_in,
                              void* d_out, int out_size, void* d_ws, size_t ws_size,
                              hipStream_t stream) {
  const float* x = (const float*)d_in[0];
  const float* ga = (const float*)d_in[1];
  const float* conv_w = (const float*)d_in[2];
  const float* conv_b = (const float*)d_in[3];
  const float* lin_w = (const float*)d_in[4];
  const float* lin_b = (const float*)d_in[5];
  float* out = (float*)d_out;
  float* outx = out + 32768;  // x passthrough region

  float* ws = (float*)d_ws;
  float* pooledpart = ws;           // 65536
  float* wT = ws + 65536;           // 16384
  float* logits = ws + 81920;       // 32768
  float* wg = ws + 114688;          // 32768
  float* xnorm = ws + 147456;       // 4096
  float* xnp = ws + 151552;         // 262144
  float* spart2 = ws + 413696;      // 8192
  float* simpart = ws + 421888;     // 2097152

  k_wt<<<64, 256, 0, stream>>>(conv_w, wT);
  k_prep<<<1024, 512, 0, stream>>>(x, wT, conv_b, outx, xnp, pooledpart);
  k_logits<<<16, 256, 0, stream>>>(pooledpart, lin_w, lin_b, ga, logits, wg);

  // iteration 1
  k_route<<<1024, 512, 0, stream>>>(x, wg, spart2, simpart);
  k_upd<0><<<256, 256, 0, stream>>>(simpart, xnp, spart2, logits, xnorm, wg, out);

  // iteration 2 (+ final softmax into d_out)
  k_route<<<1024, 512, 0, stream>>>(x, wg, spart2, simpart);
  k_upd<1><<<256, 256, 0, stream>>>(simpart, xnp, spart2, logits, xnorm, wg, out);
}

// Round 11
// 139.063 us; speedup vs baseline: 1.1788x; 1.1788x over previous
//
#include <hip/hip_runtime.h>

#define BB 16
#define CC 256
#define NN 4096
#define CN (CC*NN)
#define GG 8
#define EPSF 1e-8f
#define NT 64      // n-tile per block
#define STR 68     // padded LDS row stride (words); 16B-aligned rows
#define PSTR 65    // pool stride (odd -> conflict-free b32)

// ---------------- transpose conv_w -> wT[c][d] ----------------------------------------------
__global__ __launch_bounds__(256) void k_wt(const float* __restrict__ conv_w,
                                            float* __restrict__ wT) {
  int o = blockIdx.x * 256 + threadIdx.x;  // 16384
  int d = o >> 8, c = o & 255;
  wT[c * 64 + d] = conv_w[d * 256 + c];
}

// ---------------- prep: x passthrough + xnorm partials + conv/relu/pool --------------------
// grid: 16 b x 64 n-tiles(64). block 512 = 8 waves, 2 blocks/CU (71.7KB LDS).
// Conv: lane = d, wave owns 8 n. Weights PRELOADED to registers in 32-c chunks
// (A/B software pipeline, coalesced loads); inner loop = uniform LDS reads + reg FMA only.
__global__ __launch_bounds__(512) void k_prep(const float* __restrict__ x,
                                              const float* __restrict__ wT,
                                              const float* __restrict__ conv_b,
                                              float* __restrict__ xout,
                                              float* __restrict__ xnp,
                                              float* __restrict__ pooledpart) {
  const int b = blockIdx.x >> 6;
  const int chunk = blockIdx.x & 63;
  const int t = threadIdx.x;
  const int lane = t & 63, wv = t >> 6;  // wv 0..7
  __shared__ float xs[256 * STR];  // 69632 B
  __shared__ float pool[8 * 64];   // 2048 B

  // stage x tile: rows r = k*32 + (t>>4), float4-col j = t&15
  const float* xb = x + (size_t)b * CN + chunk * NT;
  const int r0 = t >> 4, j = t & 15;
  float4 v[8];
  float sq[8];
#pragma unroll
  for (int k = 0; k < 8; ++k)
    v[k] = *(const float4*)(xb + (size_t)(k * 32 + r0) * NN + j * 4);
#pragma unroll
  for (int k = 0; k < 8; ++k) {
    *(float4*)&xs[(k * 32 + r0) * STR + j * 4] = v[k];
    sq[k] = v[k].x * v[k].x + v[k].y * v[k].y + v[k].z * v[k].z + v[k].w * v[k].w;
  }
  float* xo = xout + (size_t)b * CN + chunk * NT;
#pragma unroll
  for (int k = 0; k < 8; ++k)
    *(float4*)(xo + (size_t)(k * 32 + r0) * NN + j * 4) = v[k];
#pragma unroll
  for (int k = 0; k < 8; ++k) {
    float s = sq[k];
    s += __shfl_xor(s, 1, 64); s += __shfl_xor(s, 2, 64);
    s += __shfl_xor(s, 4, 64); s += __shfl_xor(s, 8, 64);
    sq[k] = s;
  }
  if ((t & 15) == 0) {
    float* xp = xnp + ((size_t)b * 64 + chunk) * 256 + r0;
#pragma unroll
    for (int k = 0; k < 8; ++k) xp[k * 32] = sq[k];
  }
  const float bias = conv_b[lane];  // per-lane, coalesced
  __syncthreads();

  // conv: acc[i] = sum_c wT[c][lane] * xs[c][n0+i]
  const int n0 = __builtin_amdgcn_readfirstlane(wv) * 8;
  float acc[8];
#pragma unroll
  for (int i = 0; i < 8; ++i) acc[i] = 0.f;
  const float* wp = wT + lane;
  float wA[32], wB[32];
#pragma unroll
  for (int i = 0; i < 32; ++i) wA[i] = wp[(size_t)i * 64];  // chunk 0

#define PREP_LOADW(BUF, CH)                                            \
  { _Pragma("unroll") for (int i = 0; i < 32; ++i)                     \
      BUF[i] = wp[(size_t)((CH) * 32 + i) * 64]; }
#define PREP_COMP(BUF, CH)                                             \
  { _Pragma("unroll") for (int cc = 0; cc < 32; ++cc) {                \
      const int c = (CH) * 32 + cc;                                    \
      float4 xa = *(const float4*)&xs[c * STR + n0];                   \
      float4 xb2 = *(const float4*)&xs[c * STR + n0 + 4];              \
      float w = BUF[cc];                                               \
      acc[0] = fmaf(w, xa.x, acc[0]);  acc[1] = fmaf(w, xa.y, acc[1]); \
      acc[2] = fmaf(w, xa.z, acc[2]);  acc[3] = fmaf(w, xa.w, acc[3]); \
      acc[4] = fmaf(w, xb2.x, acc[4]); acc[5] = fmaf(w, xb2.y, acc[5]);\
      acc[6] = fmaf(w, xb2.z, acc[6]); acc[7] = fmaf(w, xb2.w, acc[7]);\
    } }

  PREP_LOADW(wB, 1)  PREP_COMP(wA, 0)
  PREP_LOADW(wA, 2)  PREP_COMP(wB, 1)
  PREP_LOADW(wB, 3)  PREP_COMP(wA, 2)
  PREP_LOADW(wA, 4)  PREP_COMP(wB, 3)
  PREP_LOADW(wB, 5)  PREP_COMP(wA, 4)
  PREP_LOADW(wA, 6)  PREP_COMP(wB, 5)
  PREP_LOADW(wB, 7)  PREP_COMP(wA, 6)
                     PREP_COMP(wB, 7)
#undef PREP_LOADW
#undef PREP_COMP

  float p = 0.f;
#pragma unroll
  for (int i = 0; i < 8; ++i) p += fmaxf(acc[i] + bias, 0.f);
  pool[wv * 64 + lane] = p;
  __syncthreads();
  if (t < 64) {
    float s = 0.f;
#pragma unroll
    for (int w = 0; w < 8; ++w) s += pool[w * 64 + t];
    pooledpart[((size_t)b * 64 + chunk) * 64 + t] = s;
  }
}

// ---------------- pooled-reduce + logits + log(ga) + softmax -> wg --------------------------
__global__ __launch_bounds__(256) void k_logits(const float* __restrict__ pooledpart,
                                                const float* __restrict__ lin_w,
                                                const float* __restrict__ lin_b,
                                                const float* __restrict__ ga,
                                                float* __restrict__ logits,
                                                float* __restrict__ wg) {
  const int b = blockIdx.x, t = threadIdx.x;
  __shared__ float ps2[4][64];
  __shared__ float ps[64];
  {
    const int d = t & 63, q = t >> 6;
    float s = 0.f;
#pragma unroll
    for (int k = 0; k < 16; ++k)
      s += pooledpart[((size_t)b * 64 + q * 16 + k) * 64 + d];
    ps2[q][d] = s;
  }
  __syncthreads();
  if (t < 64) ps[t] = (ps2[0][t] + ps2[1][t] + ps2[2][t] + ps2[3][t]) * (1.f / 4096.f);
  __syncthreads();
  const int c = t;
  float out[8];
#pragma unroll
  for (int g = 0; g < 8; ++g) {
    const float4* wr = (const float4*)(lin_w + ((size_t)c * 8 + g) * 64);
    float s = 0.f;
#pragma unroll
    for (int k4 = 0; k4 < 16; ++k4) {
      float4 wv = wr[k4];
      s += wv.x * ps[k4 * 4] + wv.y * ps[k4 * 4 + 1] + wv.z * ps[k4 * 4 + 2] +
           wv.w * ps[k4 * 4 + 3];
    }
    out[g] = s + lin_b[c * 8 + g] + logf(ga[((size_t)b * 256 + c) * 8 + g] + EPSF);
  }
  float* lp = logits + ((size_t)b * 256 + c) * 8;
  *(float4*)lp = make_float4(out[0], out[1], out[2], out[3]);
  *(float4*)(lp + 4) = make_float4(out[4], out[5], out[6], out[7]);
  float m = out[0];
#pragma unroll
  for (int g = 1; g < 8; ++g) m = fmaxf(m, out[g]);
  float sum = 0.f;
#pragma unroll
  for (int g = 0; g < 8; ++g) { out[g] = __expf(out[g] - m); sum += out[g]; }
  float r = 1.f / sum;
  float4* op = (float4*)(wg + ((size_t)b * 256 + c) * 8);
  op[0] = make_float4(out[0] * r, out[1] * r, out[2] * r, out[3] * r);
  op[1] = make_float4(out[4] * r, out[5] * r, out[6] * r, out[7] * r);
}

// ---------------- fused routing iteration: s-tile + sim partials ----------------------------
// grid: 16 b x 64 n-tiles(64). block 256. LDS 80128B -> 2 blocks/CU.
// wg staged into pool-region LDS (all-LDS phase 1, in-order lgkmcnt; no s_load mixing).
__global__ __launch_bounds__(256, 2) void k_route(const float* __restrict__ x,
                                                  const float* __restrict__ wg,
                                                  float* __restrict__ spart2,
                                                  float* __restrict__ simpart) {
  const int b = blockIdx.x >> 6;
  const int chunk = blockIdx.x & 63;
  const int t = threadIdx.x;
  const int lane = t & 63, wv = t >> 6;
  __shared__ float xs[256 * STR];      // 69632 B (reused as pool2 in merge)
  __shared__ float st[8 * STR];        // 2176 B   s tile
  __shared__ float pool[32 * PSTR];    // 8320 B: first wg stage [c*8+g], then pool1 (PSTR)

  // stage x tile + wg
  const float* xb = x + (size_t)b * CN + chunk * NT;
#pragma unroll
  for (int k = 0; k < 16; ++k) {
    int f = k * 256 + t;
    int r = f >> 4, j = f & 15;
    float4 v = *(const float4*)(xb + (size_t)r * NN + j * 4);
    *(float4*)&xs[r * STR + j * 4] = v;
  }
  {
    const float4* wsrc = (const float4*)(wg + (size_t)b * 2048);
    *(float4*)&pool[t * 8] = wsrc[t * 2];
    *(float4*)&pool[t * 8 + 4] = wsrc[t * 2 + 1];
  }
  __syncthreads();

  // ---- phase 1: per-wave s partial over c-quarter; lane owns n; w from LDS ----
  const int cq = __builtin_amdgcn_readfirstlane(wv);
  float sacc[8];
#pragma unroll
  for (int g = 0; g < 8; ++g) sacc[g] = 0.f;
  {
    const int c0 = cq * 64;
#pragma unroll 8
    for (int cc = 0; cc < 64; ++cc) {
      float xv = xs[(c0 + cc) * STR + lane];
      float4 wa = *(const float4*)&pool[(c0 + cc) * 8];      // uniform broadcast
      float4 wb = *(const float4*)&pool[(c0 + cc) * 8 + 4];
      sacc[0] = fmaf(wa.x, xv, sacc[0]);
      sacc[1] = fmaf(wa.y, xv, sacc[1]);
      sacc[2] = fmaf(wa.z, xv, sacc[2]);
      sacc[3] = fmaf(wa.w, xv, sacc[3]);
      sacc[4] = fmaf(wb.x, xv, sacc[4]);
      sacc[5] = fmaf(wb.y, xv, sacc[5]);
      sacc[6] = fmaf(wb.z, xv, sacc[6]);
      sacc[7] = fmaf(wb.w, xv, sacc[7]);
    }
  }
  __syncthreads();  // all wg reads done; pool region now reusable as pool1 (PSTR layout)
#pragma unroll
  for (int g = 0; g < 8; ++g) pool[(cq * 8 + g) * PSTR + lane] = sacc[g];
  __syncthreads();
  // finalize s-tile + spart2 (sumsq over tile n)
#pragma unroll
  for (int k = 0; k < 2; ++k) {
    int g = (t >> 6) + 4 * k;
    int n = t & 63;
    float v = pool[(0 * 8 + g) * PSTR + n] + pool[(1 * 8 + g) * PSTR + n] +
              pool[(2 * 8 + g) * PSTR + n] + pool[(3 * 8 + g) * PSTR + n];
    st[g * STR + n] = v;
    float s2 = v * v;
#pragma unroll
    for (int off = 1; off < 64; off <<= 1) s2 += __shfl_xor(s2, off, 64);
    if (n == 0) spart2[((size_t)b * 64 + chunk) * 8 + g] = s2;
  }
  __syncthreads();

  // ---- phase 2: sim partials. thread: co=t&31 (c=co+32k), nq=t>>5 (8 n each) ----
  const int co = t & 31;
  const int nq = t >> 5;
  float4 sva[8], svb[8];
#pragma unroll
  for (int g = 0; g < 8; ++g) {
    sva[g] = *(const float4*)&st[g * STR + nq * 8];
    svb[g] = *(const float4*)&st[g * STR + nq * 8 + 4];
  }
  float acc[8][8];
#pragma unroll
  for (int k = 0; k < 8; ++k)
#pragma unroll
    for (int g = 0; g < 8; ++g) acc[k][g] = 0.f;
#pragma unroll
  for (int k = 0; k < 8; ++k) {
    const int c = co + 32 * k;
    float4 xa = *(const float4*)&xs[c * STR + nq * 8];
    float4 xb2 = *(const float4*)&xs[c * STR + nq * 8 + 4];
#pragma unroll
    for (int g = 0; g < 8; ++g) {
      float a = acc[k][g];
      a = fmaf(xa.x, sva[g].x, a);
      a = fmaf(xa.y, sva[g].y, a);
      a = fmaf(xa.z, sva[g].z, a);
      a = fmaf(xa.w, sva[g].w, a);
      a = fmaf(xb2.x, svb[g].x, a);
      a = fmaf(xb2.y, svb[g].y, a);
      a = fmaf(xb2.z, svb[g].z, a);
      a = fmaf(xb2.w, svb[g].w, a);
      acc[k][g] = a;
    }
  }
  // combine nq pairs within wave (lanes l <-> l+32)
#pragma unroll
  for (int k = 0; k < 8; ++k)
#pragma unroll
    for (int g = 0; g < 8; ++g) acc[k][g] += __shfl_xor(acc[k][g], 32, 64);
  __syncthreads();  // xs reads done -> reuse as pool2[co][(k*4+wv)*8+g], stride 260
  float* pool2 = xs;
  if (lane < 32) {
#pragma unroll
    for (int k = 0; k < 8; ++k) {
      *(float4*)&pool2[co * 260 + (k * 4 + wv) * 8 + 0] =
          make_float4(acc[k][0], acc[k][1], acc[k][2], acc[k][3]);
      *(float4*)&pool2[co * 260 + (k * 4 + wv) * 8 + 4] =
          make_float4(acc[k][4], acc[k][5], acc[k][6], acc[k][7]);
    }
  }
  __syncthreads();
  // merge over waves: output c = t, g = 0..7
  {
    const int mco = t & 31, mk = t >> 5;
    float4 r0 = make_float4(0.f, 0.f, 0.f, 0.f), r1 = r0;
#pragma unroll
    for (int w = 0; w < 4; ++w) {
      float4 a = *(const float4*)&pool2[mco * 260 + (mk * 4 + w) * 8 + 0];
      float4 bq = *(const float4*)&pool2[mco * 260 + (mk * 4 + w) * 8 + 4];
      r0.x += a.x; r0.y += a.y; r0.z += a.z; r0.w += a.w;
      r1.x += bq.x; r1.y += bq.y; r1.z += bq.z; r1.w += bq.w;
    }
    float* sp = simpart + (((size_t)b * 64 + chunk) * 256 + t) * 8;
    *(float4*)sp = r0;
    *(float4*)(sp + 4) = r1;
  }
}

// ---------------- logits += sim/(xn*sn); !FINAL: softmax->wg (+xnorm); FINAL: ->d_out -------
template <int FINAL>
__global__ __launch_bounds__(256) void k_upd(const float* __restrict__ simpart,
                                             const float* __restrict__ xnp,
                                             const float* __restrict__ spart2,
                                             float* __restrict__ logits,
                                             float* __restrict__ xnorm,
                                             float* __restrict__ wg,
                                             float* __restrict__ outw) {
  const int b = blockIdx.x >> 4;
  const int c0 = (blockIdx.x & 15) * 16;
  const int t = threadIdx.x;
  __shared__ float simld[16][8];
  __shared__ float xnl[16];
  __shared__ float snr8[8];
  {
    const int pair = t >> 1, kh = t & 1;
    const int cl = pair >> 3, g = pair & 7;
    float sm = 0.f;
    const float* sp = simpart + (((size_t)b * 64 + kh * 32) * 256 + c0 + cl) * 8 + g;
#pragma unroll 8
    for (int k = 0; k < 32; ++k) sm += sp[(size_t)k * 2048];
    sm += __shfl_xor(sm, 1, 64);
    if (kh == 0) simld[cl][g] = sm;
  }
  {
    const int cl2 = t >> 4, kq = t & 15;
    if (!FINAL) {
      float p = 0.f;
#pragma unroll
      for (int j = 0; j < 4; ++j)
        p += xnp[((size_t)b * 64 + kq + 16 * j) * 256 + c0 + cl2];
      p += __shfl_xor(p, 1, 64); p += __shfl_xor(p, 2, 64);
      p += __shfl_xor(p, 4, 64); p += __shfl_xor(p, 8, 64);
      if (kq == 0) {
        float xn = fmaxf(sqrtf(p), EPSF);
        xnl[cl2] = xn;
        xnorm[b * 256 + c0 + cl2] = xn;
      }
    } else {
      if (kq == 0) xnl[cl2] = xnorm[b * 256 + c0 + cl2];
    }
  }
  if (t < 64) {
    const int g2 = t >> 3, kq = t & 7;
    float p = 0.f;
#pragma unroll
    for (int j = 0; j < 8; ++j) p += spart2[((size_t)b * 64 + kq + 8 * j) * 8 + g2];
    p += __shfl_xor(p, 1, 64); p += __shfl_xor(p, 2, 64); p += __shfl_xor(p, 4, 64);
    if (kq == 0) snr8[g2] = 1.f / fmaxf(sqrtf(p), EPSF);
  }
  __syncthreads();
  if (t < 16) {
    const int c = c0 + t;
    float* lp = logits + ((size_t)b * 256 + c) * 8;
    float4 l0 = *(const float4*)lp, l1 = *(const float4*)(lp + 4);
    float lg[8] = {l0.x, l0.y, l0.z, l0.w, l1.x, l1.y, l1.z, l1.w};
    const float xni = 1.f / xnl[t];
#pragma unroll
    for (int g = 0; g < 8; ++g) lg[g] += simld[t][g] * xni * snr8[g];
    if (!FINAL) {
      *(float4*)lp = make_float4(lg[0], lg[1], lg[2], lg[3]);
      *(float4*)(lp + 4) = make_float4(lg[4], lg[5], lg[6], lg[7]);
    }
    float m = lg[0];
#pragma unroll
    for (int g = 1; g < 8; ++g) m = fmaxf(m, lg[g]);
    float sum = 0.f;
#pragma unroll
    for (int g = 0; g < 8; ++g) { lg[g] = __expf(lg[g] - m); sum += lg[g]; }
    float r = 1.f / sum;
    float* dst = FINAL ? outw : wg;
    float4* op = (float4*)(dst + ((size_t)b * 256 + c) * 8);
    op[0] = make_float4(lg[0] * r, lg[1] * r, lg[2] * r, lg[3] * r);
    op[1] = make_float4(lg[4] * r, lg[5] * r, lg[6] * r, lg[7] * r);
  }
}

extern "C" void kernel_launch(void* const* d_in, const int* in_sizes, int n_in,
                              void* d_out, int out_size, void* d_ws, size_t ws_size,
                              hipStream_t stream) {
  const float* x = (const float*)d_in[0];
  const float* ga = (const float*)d_in[1];
  const float* conv_w = (const float*)d_in[2];
  const float* conv_b = (const float*)d_in[3];
  const float* lin_w = (const float*)d_in[4];
  const float* lin_b = (const float*)d_in[5];
  float* out = (float*)d_out;
  float* outx = out + 32768;  // x passthrough region

  float* ws = (float*)d_ws;
  float* pooledpart = ws;           // 65536
  float* wT = ws + 65536;           // 16384
  float* logits = ws + 81920;       // 32768
  float* wg = ws + 114688;          // 32768
  float* xnorm = ws + 147456;       // 4096
  float* xnp = ws + 151552;         // 262144
  float* spart2 = ws + 413696;      // 8192
  float* simpart = ws + 421888;     // 2097152

  k_wt<<<64, 256, 0, stream>>>(conv_w, wT);
  k_prep<<<1024, 512, 0, stream>>>(x, wT, conv_b, outx, xnp, pooledpart);
  k_logits<<<16, 256, 0, stream>>>(pooledpart, lin_w, lin_b, ga, logits, wg);

  // iteration 1
  k_route<<<1024, 256, 0, stream>>>(x, wg, spart2, simpart);
  k_upd<0><<<256, 256, 0, stream>>>(simpart, xnp, spart2, logits, xnorm, wg, out);

  // iteration 2 (+ final softmax into d_out)
  k_route<<<1024, 256, 0, stream>>>(x, wg, spart2, simpart);
  k_upd<1><<<256, 256, 0, stream>>>(simpart, xnp, spart2, logits, xnorm, wg, out);
}

// Round 12
// 112.207 us; speedup vs baseline: 1.4610x; 1.2393x over previous
//
#include <hip/hip_runtime.h>

#define BB 16
#define CC 256
#define NN 4096
#define CN (CC*NN)
#define GG 8
#define EPSF 1e-8f
#define NT 64      // n-tile per block
#define STR 68     // padded LDS row stride (words); 16B-aligned rows
#define PSTR 65    // pool stride (odd -> conflict-free b32)

typedef __attribute__((ext_vector_type(8))) short bf16x8;
typedef __attribute__((ext_vector_type(4))) float f32x4;
typedef __attribute__((ext_vector_type(2))) unsigned int uint32x2;

__device__ __forceinline__ unsigned short bfr(float f) {  // f32 -> bf16 RNE
  unsigned int u = __float_as_uint(f);
  return (unsigned short)((u + 0x7FFFu + ((u >> 16) & 1u)) >> 16);
}

// ---------------- conv_w f32 [64][256] -> bf16 [64][256] (no transpose) ---------------------
__global__ __launch_bounds__(256) void k_wt(const float* __restrict__ conv_w,
                                            unsigned short* __restrict__ wbf) {
  int o = blockIdx.x * 256 + threadIdx.x;  // 16384
  wbf[o] = bfr(conv_w[o]);
}

// ---------------- prep: x passthrough + xnorm partials + MFMA conv/relu/pool ----------------
// grid: 16 b x 64 n-tiles(64). block 512 = 8 waves. LDS: xbf 32KB (bf16 tile) + pool.
// X staged bf16 into [kk=c/32][nt=n/16] regions of 32x16 (row-major, 32B rows).
// Wave wv: dt = wv>>1 (16 d), nt pair {2h,2h+1}, h = wv&1. A-frag: b128 global from wbf.
// B-frag: 2x ds_read_b64_tr_b16, per-lane addr RB + (l&15)*2 + (l>>4)*256 (+128).
__global__ __launch_bounds__(512) void k_prep(const float* __restrict__ x,
                                              const unsigned short* __restrict__ wbf,
                                              const float* __restrict__ conv_b,
                                              float* __restrict__ xout,
                                              float* __restrict__ xnp,
                                              float* __restrict__ pooledpart) {
  const int b = blockIdx.x >> 6;
  const int chunk = blockIdx.x & 63;
  const int t = threadIdx.x;
  const int lane = t & 63, wv = t >> 6;  // wv 0..7
  __shared__ unsigned short xbf[16384];  // 32 KB: 32 regions x 1024B
  __shared__ float pool[8 * 16];         // 512 B

  // stage: rows c = k*32 + r0 (r0 = t>>4, 0..31), n-cols 4j..4j+3 (j = t&15)
  const float* xb = x + (size_t)b * CN + chunk * NT;
  const int r0 = t >> 4, j = t & 15;
  float4 v[8];
  float sq[8];
#pragma unroll
  for (int k = 0; k < 8; ++k)
    v[k] = *(const float4*)(xb + (size_t)(k * 32 + r0) * NN + j * 4);
#pragma unroll
  for (int k = 0; k < 8; ++k) {
    ushort4 hh;
    hh.x = bfr(v[k].x); hh.y = bfr(v[k].y); hh.z = bfr(v[k].z); hh.w = bfr(v[k].w);
    // region (kk=k, nt=j>>2): base (k*4 + (j>>2))*512 ushort; row r0: *16; col (j&3)*4
    *(ushort4*)&xbf[(k * 4 + (j >> 2)) * 512 + r0 * 16 + (j & 3) * 4] = hh;
    sq[k] = v[k].x * v[k].x + v[k].y * v[k].y + v[k].z * v[k].z + v[k].w * v[k].w;
  }
  float* xo = xout + (size_t)b * CN + chunk * NT;
#pragma unroll
  for (int k = 0; k < 8; ++k)
    *(float4*)(xo + (size_t)(k * 32 + r0) * NN + j * 4) = v[k];
#pragma unroll
  for (int k = 0; k < 8; ++k) {
    float s = sq[k];
    s += __shfl_xor(s, 1, 64); s += __shfl_xor(s, 2, 64);
    s += __shfl_xor(s, 4, 64); s += __shfl_xor(s, 8, 64);
    sq[k] = s;
  }
  if ((t & 15) == 0) {
    float* xp = xnp + ((size_t)b * 64 + chunk) * 256 + r0;
#pragma unroll
    for (int k = 0; k < 8; ++k) xp[k * 32] = sq[k];
  }
  __syncthreads();

  // MFMA conv: D[d][n] = sum_c W[d][c] * X[c][n]
  const int dt = wv >> 1, h2 = wv & 1;
  const int g = lane >> 4, col = lane & 15;
  const int drow = dt * 16 + col;  // A row (d) = lane&15
  union AF { uint4 q; bf16x8 v; } a[8];
  const uint4* wq = (const uint4*)wbf;  // 16B units; idx = d*32 + kk*4 + g
#pragma unroll
  for (int kk = 0; kk < 8; ++kk) a[kk].q = wq[drow * 32 + kk * 4 + g];

  f32x4 acc0 = {0.f, 0.f, 0.f, 0.f}, acc1 = {0.f, 0.f, 0.f, 0.f};
  const unsigned int xbase = (unsigned int)(size_t)&xbf[0];
  const unsigned int lanoff = (unsigned int)(col * 2 + g * 256);
#pragma unroll
  for (int kk = 0; kk < 8; ++kk) {
    const unsigned int ra = xbase + (unsigned int)((kk * 4 + 2 * h2) * 1024) + lanoff;
    const unsigned int rb = ra + 1024;  // nt+1 region
    union BF { uint32x2 tr[2]; bf16x8 v; } b0, b1;
    asm volatile("ds_read_b64_tr_b16 %0, %1" : "=v"(b0.tr[0]) : "v"(ra));
    asm volatile("ds_read_b64_tr_b16 %0, %1" : "=v"(b0.tr[1]) : "v"(ra + 128));
    asm volatile("ds_read_b64_tr_b16 %0, %1" : "=v"(b1.tr[0]) : "v"(rb));
    asm volatile("ds_read_b64_tr_b16 %0, %1" : "=v"(b1.tr[1]) : "v"(rb + 128));
    asm volatile("s_waitcnt lgkmcnt(0)" ::: "memory");
    __builtin_amdgcn_sched_barrier(0);
    acc0 = __builtin_amdgcn_mfma_f32_16x16x32_bf16(a[kk].v, b0.v, acc0, 0, 0, 0);
    acc1 = __builtin_amdgcn_mfma_f32_16x16x32_bf16(a[kk].v, b1.v, acc1, 0, 0, 0);
  }
  // epilogue: bias+relu, sum over n (cols), pool across nt-halves
  const float4 bias = *(const float4*)(conv_b + dt * 16 + 4 * g);  // d = dt*16+4g+r
  const float br[4] = {bias.x, bias.y, bias.z, bias.w};
  float hs[4];
#pragma unroll
  for (int r = 0; r < 4; ++r) {
    float hv = fmaxf(acc0[r] + br[r], 0.f) + fmaxf(acc1[r] + br[r], 0.f);
    hv += __shfl_xor(hv, 1, 64); hv += __shfl_xor(hv, 2, 64);
    hv += __shfl_xor(hv, 4, 64); hv += __shfl_xor(hv, 8, 64);
    hs[r] = hv;
  }
  if (col == 0) {
#pragma unroll
    for (int r = 0; r < 4; ++r) pool[wv * 16 + g * 4 + r] = hs[r];
  }
  __syncthreads();
  if (t < 64) {
    const int dtt = t >> 4, idx = t & 15;
    pooledpart[((size_t)b * 64 + chunk) * 64 + t] =
        pool[(dtt * 2) * 16 + idx] + pool[(dtt * 2 + 1) * 16 + idx];
  }
}

// ---------------- pooled-reduce + logits + log(ga) + softmax -> wg --------------------------
__global__ __launch_bounds__(256) void k_logits(const float* __restrict__ pooledpart,
                                                const float* __restrict__ lin_w,
                                                const float* __restrict__ lin_b,
                                                const float* __restrict__ ga,
                                                float* __restrict__ logits,
                                                float* __restrict__ wg) {
  const int b = blockIdx.x, t = threadIdx.x;
  __shared__ float ps2[4][64];
  __shared__ float ps[64];
  {
    const int d = t & 63, q = t >> 6;
    float s = 0.f;
#pragma unroll
    for (int k = 0; k < 16; ++k)
      s += pooledpart[((size_t)b * 64 + q * 16 + k) * 64 + d];
    ps2[q][d] = s;
  }
  __syncthreads();
  if (t < 64) ps[t] = (ps2[0][t] + ps2[1][t] + ps2[2][t] + ps2[3][t]) * (1.f / 4096.f);
  __syncthreads();
  const int c = t;
  float out[8];
#pragma unroll
  for (int g = 0; g < 8; ++g) {
    const float4* wr = (const float4*)(lin_w + ((size_t)c * 8 + g) * 64);
    float s = 0.f;
#pragma unroll
    for (int k4 = 0; k4 < 16; ++k4) {
      float4 wv = wr[k4];
      s += wv.x * ps[k4 * 4] + wv.y * ps[k4 * 4 + 1] + wv.z * ps[k4 * 4 + 2] +
           wv.w * ps[k4 * 4 + 3];
    }
    out[g] = s + lin_b[c * 8 + g] + logf(ga[((size_t)b * 256 + c) * 8 + g] + EPSF);
  }
  float* lp = logits + ((size_t)b * 256 + c) * 8;
  *(float4*)lp = make_float4(out[0], out[1], out[2], out[3]);
  *(float4*)(lp + 4) = make_float4(out[4], out[5], out[6], out[7]);
  float m = out[0];
#pragma unroll
  for (int g = 1; g < 8; ++g) m = fmaxf(m, out[g]);
  float sum = 0.f;
#pragma unroll
  for (int g = 0; g < 8; ++g) { out[g] = __expf(out[g] - m); sum += out[g]; }
  float r = 1.f / sum;
  float4* op = (float4*)(wg + ((size_t)b * 256 + c) * 8);
  op[0] = make_float4(out[0] * r, out[1] * r, out[2] * r, out[3] * r);
  op[1] = make_float4(out[4] * r, out[5] * r, out[6] * r, out[7] * r);
}

// ---------------- fused routing iteration: s-tile + sim partials ----------------------------
// grid: 16 b x 64 n-tiles(64). block 256. LDS 80128B -> 2 blocks/CU.
__global__ __launch_bounds__(256, 2) void k_route(const float* __restrict__ x,
                                                  const float* __restrict__ wg,
                                                  float* __restrict__ spart2,
                                                  float* __restrict__ simpart) {
  const int b = blockIdx.x >> 6;
  const int chunk = blockIdx.x & 63;
  const int t = threadIdx.x;
  const int lane = t & 63, wv = t >> 6;
  __shared__ float xs[256 * STR];      // 69632 B (reused as pool2 in merge)
  __shared__ float st[8 * STR];        // 2176 B   s tile
  __shared__ float pool[32 * PSTR];    // 8320 B: wg stage [c*8+g], then pool1 (PSTR)

  const float* xb = x + (size_t)b * CN + chunk * NT;
#pragma unroll
  for (int k = 0; k < 16; ++k) {
    int f = k * 256 + t;
    int r = f >> 4, jj = f & 15;
    float4 v = *(const float4*)(xb + (size_t)r * NN + jj * 4);
    *(float4*)&xs[r * STR + jj * 4] = v;
  }
  {
    const float4* wsrc = (const float4*)(wg + (size_t)b * 2048);
    *(float4*)&pool[t * 8] = wsrc[t * 2];
    *(float4*)&pool[t * 8 + 4] = wsrc[t * 2 + 1];
  }
  __syncthreads();

  const int cq = __builtin_amdgcn_readfirstlane(wv);
  float sacc[8];
#pragma unroll
  for (int g = 0; g < 8; ++g) sacc[g] = 0.f;
  {
    const int c0 = cq * 64;
#pragma unroll 8
    for (int cc = 0; cc < 64; ++cc) {
      float xv = xs[(c0 + cc) * STR + lane];
      float4 wa = *(const float4*)&pool[(c0 + cc) * 8];
      float4 wb = *(const float4*)&pool[(c0 + cc) * 8 + 4];
      sacc[0] = fmaf(wa.x, xv, sacc[0]);
      sacc[1] = fmaf(wa.y, xv, sacc[1]);
      sacc[2] = fmaf(wa.z, xv, sacc[2]);
      sacc[3] = fmaf(wa.w, xv, sacc[3]);
      sacc[4] = fmaf(wb.x, xv, sacc[4]);
      sacc[5] = fmaf(wb.y, xv, sacc[5]);
      sacc[6] = fmaf(wb.z, xv, sacc[6]);
      sacc[7] = fmaf(wb.w, xv, sacc[7]);
    }
  }
  __syncthreads();
#pragma unroll
  for (int g = 0; g < 8; ++g) pool[(cq * 8 + g) * PSTR + lane] = sacc[g];
  __syncthreads();
#pragma unroll
  for (int k = 0; k < 2; ++k) {
    int g = (t >> 6) + 4 * k;
    int n = t & 63;
    float v = pool[(0 * 8 + g) * PSTR + n] + pool[(1 * 8 + g) * PSTR + n] +
              pool[(2 * 8 + g) * PSTR + n] + pool[(3 * 8 + g) * PSTR + n];
    st[g * STR + n] = v;
    float s2 = v * v;
#pragma unroll
    for (int off = 1; off < 64; off <<= 1) s2 += __shfl_xor(s2, off, 64);
    if (n == 0) spart2[((size_t)b * 64 + chunk) * 8 + g] = s2;
  }
  __syncthreads();

  const int co = t & 31;
  const int nq = t >> 5;
  float4 sva[8], svb[8];
#pragma unroll
  for (int g = 0; g < 8; ++g) {
    sva[g] = *(const float4*)&st[g * STR + nq * 8];
    svb[g] = *(const float4*)&st[g * STR + nq * 8 + 4];
  }
  float acc[8][8];
#pragma unroll
  for (int k = 0; k < 8; ++k)
#pragma unroll
    for (int g = 0; g < 8; ++g) acc[k][g] = 0.f;
#pragma unroll
  for (int k = 0; k < 8; ++k) {
    const int c = co + 32 * k;
    float4 xa = *(const float4*)&xs[c * STR + nq * 8];
    float4 xb2 = *(const float4*)&xs[c * STR + nq * 8 + 4];
#pragma unroll
    for (int g = 0; g < 8; ++g) {
      float a = acc[k][g];
      a = fmaf(xa.x, sva[g].x, a);
      a = fmaf(xa.y, sva[g].y, a);
      a = fmaf(xa.z, sva[g].z, a);
      a = fmaf(xa.w, sva[g].w, a);
      a = fmaf(xb2.x, svb[g].x, a);
      a = fmaf(xb2.y, svb[g].y, a);
      a = fmaf(xb2.z, svb[g].z, a);
      a = fmaf(xb2.w, svb[g].w, a);
      acc[k][g] = a;
    }
  }
#pragma unroll
  for (int k = 0; k < 8; ++k)
#pragma unroll
    for (int g = 0; g < 8; ++g) acc[k][g] += __shfl_xor(acc[k][g], 32, 64);
  __syncthreads();
  float* pool2 = xs;
  if (lane < 32) {
#pragma unroll
    for (int k = 0; k < 8; ++k) {
      *(float4*)&pool2[co * 260 + (k * 4 + wv) * 8 + 0] =
          make_float4(acc[k][0], acc[k][1], acc[k][2], acc[k][3]);
      *(float4*)&pool2[co * 260 + (k * 4 + wv) * 8 + 4] =
          make_float4(acc[k][4], acc[k][5], acc[k][6], acc[k][7]);
    }
  }
  __syncthreads();
  {
    const int mco = t & 31, mk = t >> 5;
    float4 r0 = make_float4(0.f, 0.f, 0.f, 0.f), r1 = r0;
#pragma unroll
    for (int w = 0; w < 4; ++w) {
      float4 a = *(const float4*)&pool2[mco * 260 + (mk * 4 + w) * 8 + 0];
      float4 bq = *(const float4*)&pool2[mco * 260 + (mk * 4 + w) * 8 + 4];
      r0.x += a.x; r0.y += a.y; r0.z += a.z; r0.w += a.w;
      r1.x += bq.x; r1.y += bq.y; r1.z += bq.z; r1.w += bq.w;
    }
    float* sp = simpart + (((size_t)b * 64 + chunk) * 256 + t) * 8;
    *(float4*)sp = r0;
    *(float4*)(sp + 4) = r1;
  }
}

// ---------------- logits += sim/(xn*sn); !FINAL: softmax->wg (+xnorm); FINAL: ->d_out -------
template <int FINAL>
__global__ __launch_bounds__(256) void k_upd(const float* __restrict__ simpart,
                                             const float* __restrict__ xnp,
                                             const float* __restrict__ spart2,
                                             float* __restrict__ logits,
                                             float* __restrict__ xnorm,
                                             float* __restrict__ wg,
                                             float* __restrict__ outw) {
  const int b = blockIdx.x >> 4;
  const int c0 = (blockIdx.x & 15) * 16;
  const int t = threadIdx.x;
  __shared__ float simld[16][8];
  __shared__ float xnl[16];
  __shared__ float snr8[8];
  {
    const int pair = t >> 1, kh = t & 1;
    const int cl = pair >> 3, g = pair & 7;
    float sm = 0.f;
    const float* sp = simpart + (((size_t)b * 64 + kh * 32) * 256 + c0 + cl) * 8 + g;
#pragma unroll 8
    for (int k = 0; k < 32; ++k) sm += sp[(size_t)k * 2048];
    sm += __shfl_xor(sm, 1, 64);
    if (kh == 0) simld[cl][g] = sm;
  }
  {
    const int cl2 = t >> 4, kq = t & 15;
    if (!FINAL) {
      float p = 0.f;
#pragma unroll
      for (int jj = 0; jj < 4; ++jj)
        p += xnp[((size_t)b * 64 + kq + 16 * jj) * 256 + c0 + cl2];
      p += __shfl_xor(p, 1, 64); p += __shfl_xor(p, 2, 64);
      p += __shfl_xor(p, 4, 64); p += __shfl_xor(p, 8, 64);
      if (kq == 0) {
        float xn = fmaxf(sqrtf(p), EPSF);
        xnl[cl2] = xn;
        xnorm[b * 256 + c0 + cl2] = xn;
      }
    } else {
      if (kq == 0) xnl[cl2] = xnorm[b * 256 + c0 + cl2];
    }
  }
  if (t < 64) {
    const int g2 = t >> 3, kq = t & 7;
    float p = 0.f;
#pragma unroll
    for (int jj = 0; jj < 8; ++jj) p += spart2[((size_t)b * 64 + kq + 8 * jj) * 8 + g2];
    p += __shfl_xor(p, 1, 64); p += __shfl_xor(p, 2, 64); p += __shfl_xor(p, 4, 64);
    if (kq == 0) snr8[g2] = 1.f / fmaxf(sqrtf(p), EPSF);
  }
  __syncthreads();
  if (t < 16) {
    const int c = c0 + t;
    float* lp = logits + ((size_t)b * 256 + c) * 8;
    float4 l0 = *(const float4*)lp, l1 = *(const float4*)(lp + 4);
    float lg[8] = {l0.x, l0.y, l0.z, l0.w, l1.x, l1.y, l1.z, l1.w};
    const float xni = 1.f / xnl[t];
#pragma unroll
    for (int g = 0; g < 8; ++g) lg[g] += simld[t][g] * xni * snr8[g];
    if (!FINAL) {
      *(float4*)lp = make_float4(lg[0], lg[1], lg[2], lg[3]);
      *(float4*)(lp + 4) = make_float4(lg[4], lg[5], lg[6], lg[7]);
    }
    float m = lg[0];
#pragma unroll
    for (int g = 1; g < 8; ++g) m = fmaxf(m, lg[g]);
    float sum = 0.f;
#pragma unroll
    for (int g = 0; g < 8; ++g) { lg[g] = __expf(lg[g] - m); sum += lg[g]; }
    float r = 1.f / sum;
    float* dst = FINAL ? outw : wg;
    float4* op = (float4*)(dst + ((size_t)b * 256 + c) * 8);
    op[0] = make_float4(lg[0] * r, lg[1] * r, lg[2] * r, lg[3] * r);
    op[1] = make_float4(lg[4] * r, lg[5] * r, lg[6] * r, lg[7] * r);
  }
}

extern "C" void kernel_launch(void* const* d_in, const int* in_sizes, int n_in,
                              void* d_out, int out_size, void* d_ws, size_t ws_size,
                              hipStream_t stream) {
  const float* x = (const float*)d_in[0];
  const float* ga = (const float*)d_in[1];
  const float* conv_w = (const float*)d_in[2];
  const float* conv_b = (const float*)d_in[3];
  const float* lin_w = (const float*)d_in[4];
  const float* lin_b = (const float*)d_in[5];
  float* out = (float*)d_out;
  float* outx = out + 32768;  // x passthrough region

  float* ws = (float*)d_ws;
  float* pooledpart = ws;                              // 65536
  unsigned short* wbf = (unsigned short*)(ws + 65536); // 16384 ushort (8192 floats)
  float* logits = ws + 81920;       // 32768
  float* wg = ws + 114688;          // 32768
  float* xnorm = ws + 147456;       // 4096
  float* xnp = ws + 151552;         // 262144
  float* spart2 = ws + 413696;      // 8192
  float* simpart = ws + 421888;     // 2097152

  k_wt<<<64, 256, 0, stream>>>(conv_w, wbf);
  k_prep<<<1024, 512, 0, stream>>>(x, wbf, conv_b, outx, xnp, pooledpart);
  k_logits<<<16, 256, 0, stream>>>(pooledpart, lin_w, lin_b, ga, logits, wg);

  // iteration 1
  k_route<<<1024, 256, 0, stream>>>(x, wg, spart2, simpart);
  k_upd<0><<<256, 256, 0, stream>>>(simpart, xnp, spart2, logits, xnorm, wg, out);

  // iteration 2 (+ final softmax into d_out)
  k_route<<<1024, 256, 0, stream>>>(x, wg, spart2, simpart);
  k_upd<1><<<256, 256, 0, stream>>>(simpart, xnp, spart2, logits, xnorm, wg, out);
}

// Round 13
// 95.502 us; speedup vs baseline: 1.7165x; 1.1749x over previous
//
#include <hip/hip_runtime.h>

#define BB 16
#define CC 256
#define NN 4096
#define CN (CC*NN)
#define GG 8
#define EPSF 1e-8f
#define NT 64

typedef __attribute__((ext_vector_type(8))) short bf16x8;
typedef __attribute__((ext_vector_type(4))) float f32x4;
typedef __attribute__((ext_vector_type(2))) unsigned int uint32x2;

__device__ __forceinline__ unsigned short bfr(float f) {  // f32 -> bf16 RNE
  unsigned int u = __float_as_uint(f);
  return (unsigned short)((u + 0x7FFFu + ((u >> 16) & 1u)) >> 16);
}

// ---------------- conv_w f32 [64][256] -> bf16 [64][256] ------------------------------------
__global__ __launch_bounds__(256) void k_wt(const float* __restrict__ conv_w,
                                            unsigned short* __restrict__ wbf) {
  int o = blockIdx.x * 256 + threadIdx.x;  // 16384
  wbf[o] = bfr(conv_w[o]);
}

// ---------------- prep: x passthrough + xnorm partials + MFMA conv/relu/pool ----------------
// (unchanged from R12 — validated)
__global__ __launch_bounds__(512) void k_prep(const float* __restrict__ x,
                                              const unsigned short* __restrict__ wbf,
                                              const float* __restrict__ conv_b,
                                              float* __restrict__ xout,
                                              float* __restrict__ xnp,
                                              float* __restrict__ pooledpart) {
  const int b = blockIdx.x >> 6;
  const int chunk = blockIdx.x & 63;
  const int t = threadIdx.x;
  const int lane = t & 63, wv = t >> 6;
  __shared__ unsigned short xbf[16384];  // 32 KB: 32 regions x 1024B
  __shared__ float pool[8 * 16];

  const float* xb = x + (size_t)b * CN + chunk * NT;
  const int r0 = t >> 4, j = t & 15;
  float4 v[8];
  float sq[8];
#pragma unroll
  for (int k = 0; k < 8; ++k)
    v[k] = *(const float4*)(xb + (size_t)(k * 32 + r0) * NN + j * 4);
#pragma unroll
  for (int k = 0; k < 8; ++k) {
    ushort4 hh;
    hh.x = bfr(v[k].x); hh.y = bfr(v[k].y); hh.z = bfr(v[k].z); hh.w = bfr(v[k].w);
    *(ushort4*)&xbf[(k * 4 + (j >> 2)) * 512 + r0 * 16 + (j & 3) * 4] = hh;
    sq[k] = v[k].x * v[k].x + v[k].y * v[k].y + v[k].z * v[k].z + v[k].w * v[k].w;
  }
  float* xo = xout + (size_t)b * CN + chunk * NT;
#pragma unroll
  for (int k = 0; k < 8; ++k)
    *(float4*)(xo + (size_t)(k * 32 + r0) * NN + j * 4) = v[k];
#pragma unroll
  for (int k = 0; k < 8; ++k) {
    float s = sq[k];
    s += __shfl_xor(s, 1, 64); s += __shfl_xor(s, 2, 64);
    s += __shfl_xor(s, 4, 64); s += __shfl_xor(s, 8, 64);
    sq[k] = s;
  }
  if ((t & 15) == 0) {
    float* xp = xnp + ((size_t)b * 64 + chunk) * 256 + r0;
#pragma unroll
    for (int k = 0; k < 8; ++k) xp[k * 32] = sq[k];
  }
  __syncthreads();

  const int dt = wv >> 1, h2 = wv & 1;
  const int g = lane >> 4, col = lane & 15;
  const int drow = dt * 16 + col;
  union AF { uint4 q; bf16x8 v; } a[8];
  const uint4* wq = (const uint4*)wbf;
#pragma unroll
  for (int kk = 0; kk < 8; ++kk) a[kk].q = wq[drow * 32 + kk * 4 + g];

  f32x4 acc0 = {0.f, 0.f, 0.f, 0.f}, acc1 = {0.f, 0.f, 0.f, 0.f};
  const unsigned int xbase = (unsigned int)(size_t)&xbf[0];
  const unsigned int lanoff = (unsigned int)(col * 2 + g * 256);
#pragma unroll
  for (int kk = 0; kk < 8; ++kk) {
    const unsigned int ra = xbase + (unsigned int)((kk * 4 + 2 * h2) * 1024) + lanoff;
    const unsigned int rb = ra + 1024;
    union BF { uint32x2 tr[2]; bf16x8 v; } b0, b1;
    asm volatile("ds_read_b64_tr_b16 %0, %1" : "=v"(b0.tr[0]) : "v"(ra));
    asm volatile("ds_read_b64_tr_b16 %0, %1" : "=v"(b0.tr[1]) : "v"(ra + 128));
    asm volatile("ds_read_b64_tr_b16 %0, %1" : "=v"(b1.tr[0]) : "v"(rb));
    asm volatile("ds_read_b64_tr_b16 %0, %1" : "=v"(b1.tr[1]) : "v"(rb + 128));
    asm volatile("s_waitcnt lgkmcnt(0)" ::: "memory");
    __builtin_amdgcn_sched_barrier(0);
    acc0 = __builtin_amdgcn_mfma_f32_16x16x32_bf16(a[kk].v, b0.v, acc0, 0, 0, 0);
    acc1 = __builtin_amdgcn_mfma_f32_16x16x32_bf16(a[kk].v, b1.v, acc1, 0, 0, 0);
  }
  const float4 bias = *(const float4*)(conv_b + dt * 16 + 4 * g);
  const float br[4] = {bias.x, bias.y, bias.z, bias.w};
  float hs[4];
#pragma unroll
  for (int r = 0; r < 4; ++r) {
    float hv = fmaxf(acc0[r] + br[r], 0.f) + fmaxf(acc1[r] + br[r], 0.f);
    hv += __shfl_xor(hv, 1, 64); hv += __shfl_xor(hv, 2, 64);
    hv += __shfl_xor(hv, 4, 64); hv += __shfl_xor(hv, 8, 64);
    hs[r] = hv;
  }
  if (col == 0) {
#pragma unroll
    for (int r = 0; r < 4; ++r) pool[wv * 16 + g * 4 + r] = hs[r];
  }
  __syncthreads();
  if (t < 64) {
    const int dtt = t >> 4, idx = t & 15;
    pooledpart[((size_t)b * 64 + chunk) * 64 + t] =
        pool[(dtt * 2) * 16 + idx] + pool[(dtt * 2 + 1) * 16 + idx];
  }
}

// ---------------- pooled-reduce + logits + softmax -> wgT (bf16 [16][256], rows 8-15 = 0) ---
__global__ __launch_bounds__(256) void k_logits(const float* __restrict__ pooledpart,
                                                const float* __restrict__ lin_w,
                                                const float* __restrict__ lin_b,
                                                const float* __restrict__ ga,
                                                float* __restrict__ logits,
                                                unsigned short* __restrict__ wgT) {
  const int b = blockIdx.x, t = threadIdx.x;
  __shared__ float ps2[4][64];
  __shared__ float ps[64];
  {
    const int d = t & 63, q = t >> 6;
    float s = 0.f;
#pragma unroll
    for (int k = 0; k < 16; ++k)
      s += pooledpart[((size_t)b * 64 + q * 16 + k) * 64 + d];
    ps2[q][d] = s;
  }
  __syncthreads();
  if (t < 64) ps[t] = (ps2[0][t] + ps2[1][t] + ps2[2][t] + ps2[3][t]) * (1.f / 4096.f);
  __syncthreads();
  const int c = t;
  float out[8];
#pragma unroll
  for (int g = 0; g < 8; ++g) {
    const float4* wr = (const float4*)(lin_w + ((size_t)c * 8 + g) * 64);
    float s = 0.f;
#pragma unroll
    for (int k4 = 0; k4 < 16; ++k4) {
      float4 wv = wr[k4];
      s += wv.x * ps[k4 * 4] + wv.y * ps[k4 * 4 + 1] + wv.z * ps[k4 * 4 + 2] +
           wv.w * ps[k4 * 4 + 3];
    }
    out[g] = s + lin_b[c * 8 + g] + logf(ga[((size_t)b * 256 + c) * 8 + g] + EPSF);
  }
  float* lp = logits + ((size_t)b * 256 + c) * 8;
  *(float4*)lp = make_float4(out[0], out[1], out[2], out[3]);
  *(float4*)(lp + 4) = make_float4(out[4], out[5], out[6], out[7]);
  float m = out[0];
#pragma unroll
  for (int g = 1; g < 8; ++g) m = fmaxf(m, out[g]);
  float sum = 0.f;
#pragma unroll
  for (int g = 0; g < 8; ++g) { out[g] = __expf(out[g] - m); sum += out[g]; }
  float r = 1.f / sum;
  unsigned short* wb = wgT + (size_t)b * 4096;
#pragma unroll
  for (int g = 0; g < 8; ++g) wb[g * 256 + c] = bfr(out[g] * r);
#pragma unroll
  for (int g = 8; g < 16; ++g) wb[g * 256 + c] = 0;
}

// ---------------- fused routing iteration, MFMA: s-tile + sim partials ----------------------
// grid: 16 b x 64 n-tiles(64). block 512 = 8 waves. LDS ~34.3KB.
// Phase 1 (waves 0-3): s[g][n] via mfma(A=wgT[g][c], B=tr_read X regions).
// Phase 2 (all): sim[c][g] via mfma(A=xbf rows, B=tr_read S regions).
__global__ __launch_bounds__(512) void k_route(const float* __restrict__ x,
                                               const unsigned short* __restrict__ wgT,
                                               float* __restrict__ spart2,
                                               float* __restrict__ simpart) {
  const int b = blockIdx.x >> 6;
  const int chunk = blockIdx.x & 63;
  const int t = threadIdx.x;
  const int lane = t & 63, wv = t >> 6;
  const int col = lane & 15, grp = lane >> 4;
  __shared__ unsigned short xbf[16384];  // 32KB: 32 regions [kk=c/32][nt=n/16], 32x16 each
  __shared__ unsigned short stb[1024];   // 2KB: 2 regions [kh=n/32], rows n(32) x cols g(16)
  __shared__ float spool[64];            // [nt][16 g]

  // stage x tile -> bf16 regions (identical layout to k_prep)
  {
    const float* xb = x + (size_t)b * CN + chunk * NT;
    const int r0 = t >> 4, j = t & 15;
#pragma unroll
    for (int k = 0; k < 8; ++k) {
      float4 v = *(const float4*)(xb + (size_t)(k * 32 + r0) * NN + j * 4);
      ushort4 hh;
      hh.x = bfr(v.x); hh.y = bfr(v.y); hh.z = bfr(v.z); hh.w = bfr(v.w);
      *(ushort4*)&xbf[(k * 4 + (j >> 2)) * 512 + r0 * 16 + (j & 3) * 4] = hh;
    }
  }
  __syncthreads();

  const unsigned int xbase = (unsigned int)(size_t)&xbf[0];
  const unsigned int sbase = (unsigned int)(size_t)&stb[0];
  const unsigned int lanoff = (unsigned int)(col * 2 + grp * 256);

  // ---- phase 1: waves 0-3, nt = wv ----
  if (wv < 4) {
    const int nt = wv;
    union AF { uint4 q; bf16x8 v; } a[8];
    const uint4* wq = (const uint4*)(wgT + (size_t)b * 4096);  // [g][c], row = 32 uint4
#pragma unroll
    for (int kk = 0; kk < 8; ++kk) a[kk].q = wq[col * 32 + kk * 4 + grp];
    f32x4 acc = {0.f, 0.f, 0.f, 0.f};
#pragma unroll
    for (int kk = 0; kk < 8; ++kk) {
      const unsigned int ra = xbase + (unsigned int)((kk * 4 + nt) * 1024) + lanoff;
      union BF { uint32x2 tr[2]; bf16x8 v; } bf;
      asm volatile("ds_read_b64_tr_b16 %0, %1" : "=v"(bf.tr[0]) : "v"(ra));
      asm volatile("ds_read_b64_tr_b16 %0, %1" : "=v"(bf.tr[1]) : "v"(ra + 128));
      asm volatile("s_waitcnt lgkmcnt(0)" ::: "memory");
      __builtin_amdgcn_sched_barrier(0);
      acc = __builtin_amdgcn_mfma_f32_16x16x32_bf16(a[kk].v, bf.v, acc, 0, 0, 0);
    }
    // acc[r] = s[g=4grp+r][n=nt*16+col]; store to stb region [n][g] + s^2 reduce
    {
      ushort4 sv4;
      sv4.x = bfr(acc[0]); sv4.y = bfr(acc[1]); sv4.z = bfr(acc[2]); sv4.w = bfr(acc[3]);
      *(ushort4*)&stb[(nt >> 1) * 512 + ((nt & 1) * 16 + col) * 16 + 4 * grp] = sv4;
      float s2[4];
#pragma unroll
      for (int r = 0; r < 4; ++r) {
        float vv = acc[r] * acc[r];
        vv += __shfl_xor(vv, 1, 64); vv += __shfl_xor(vv, 2, 64);
        vv += __shfl_xor(vv, 4, 64); vv += __shfl_xor(vv, 8, 64);
        s2[r] = vv;
      }
      if (col == 0) {
#pragma unroll
        for (int r = 0; r < 4; ++r) spool[nt * 16 + 4 * grp + r] = s2[r];
      }
    }
  }
  __syncthreads();
  if (t < 8)
    spart2[((size_t)b * 64 + chunk) * 8 + t] =
        spool[t] + spool[16 + t] + spool[32 + t] + spool[48 + t];

  // ---- phase 2: all 8 waves, mc = wv*2 + m2 ----
  float* sp = simpart + ((size_t)b * 64 + chunk) * 2048;
#pragma unroll
  for (int m2 = 0; m2 < 2; ++m2) {
    const int mc = wv * 2 + m2;
    const int kkA = mc >> 1;
    const int rowin = (mc & 1) * 16 + col;
    f32x4 acc = {0.f, 0.f, 0.f, 0.f};
#pragma unroll
    for (int kh = 0; kh < 2; ++kh) {
      union AF { uint4 q; bf16x8 v; } aa;
      aa.q = *(const uint4*)&xbf[(kkA * 4 + kh * 2 + (grp >> 1)) * 512 + rowin * 16 +
                                 (grp & 1) * 8];
      const unsigned int rb = sbase + (unsigned int)(kh * 1024) + lanoff;
      union BF { uint32x2 tr[2]; bf16x8 v; } bs;
      asm volatile("ds_read_b64_tr_b16 %0, %1" : "=v"(bs.tr[0]) : "v"(rb));
      asm volatile("ds_read_b64_tr_b16 %0, %1" : "=v"(bs.tr[1]) : "v"(rb + 128));
      asm volatile("s_waitcnt lgkmcnt(0)" ::: "memory");
      __builtin_amdgcn_sched_barrier(0);
      acc = __builtin_amdgcn_mfma_f32_16x16x32_bf16(aa.v, bs.v, acc, 0, 0, 0);
    }
    // acc[r] = sim[c = mc*16 + 4grp + r][g = col], valid g < 8
    if (col < 8) {
#pragma unroll
      for (int r = 0; r < 4; ++r)
        sp[(size_t)(mc * 16 + 4 * grp + r) * 8 + col] = acc[r];
    }
  }
}

// ---------------- logits += sim/(xn*sn); !FINAL: softmax->wgT (+xnorm); FINAL: ->d_out ------
template <int FINAL>
__global__ __launch_bounds__(256) void k_upd(const float* __restrict__ simpart,
                                             const float* __restrict__ xnp,
                                             const float* __restrict__ spart2,
                                             float* __restrict__ logits,
                                             float* __restrict__ xnorm,
                                             unsigned short* __restrict__ wgT,
                                             float* __restrict__ outw) {
  const int b = blockIdx.x >> 4;
  const int c0 = (blockIdx.x & 15) * 16;
  const int t = threadIdx.x;
  __shared__ float simld[16][8];
  __shared__ float xnl[16];
  __shared__ float snr8[8];
  {
    const int pair = t >> 1, kh = t & 1;
    const int cl = pair >> 3, g = pair & 7;
    float sm = 0.f;
    const float* sp = simpart + (((size_t)b * 64 + kh * 32) * 256 + c0 + cl) * 8 + g;
#pragma unroll 8
    for (int k = 0; k < 32; ++k) sm += sp[(size_t)k * 2048];
    sm += __shfl_xor(sm, 1, 64);
    if (kh == 0) simld[cl][g] = sm;
  }
  {
    const int cl2 = t >> 4, kq = t & 15;
    if (!FINAL) {
      float p = 0.f;
#pragma unroll
      for (int jj = 0; jj < 4; ++jj)
        p += xnp[((size_t)b * 64 + kq + 16 * jj) * 256 + c0 + cl2];
      p += __shfl_xor(p, 1, 64); p += __shfl_xor(p, 2, 64);
      p += __shfl_xor(p, 4, 64); p += __shfl_xor(p, 8, 64);
      if (kq == 0) {
        float xn = fmaxf(sqrtf(p), EPSF);
        xnl[cl2] = xn;
        xnorm[b * 256 + c0 + cl2] = xn;
      }
    } else {
      if (kq == 0) xnl[cl2] = xnorm[b * 256 + c0 + cl2];
    }
  }
  if (t < 64) {
    const int g2 = t >> 3, kq = t & 7;
    float p = 0.f;
#pragma unroll
    for (int jj = 0; jj < 8; ++jj) p += spart2[((size_t)b * 64 + kq + 8 * jj) * 8 + g2];
    p += __shfl_xor(p, 1, 64); p += __shfl_xor(p, 2, 64); p += __shfl_xor(p, 4, 64);
    if (kq == 0) snr8[g2] = 1.f / fmaxf(sqrtf(p), EPSF);
  }
  __syncthreads();
  if (t < 16) {
    const int c = c0 + t;
    float* lp = logits + ((size_t)b * 256 + c) * 8;
    float4 l0 = *(const float4*)lp, l1 = *(const float4*)(lp + 4);
    float lg[8] = {l0.x, l0.y, l0.z, l0.w, l1.x, l1.y, l1.z, l1.w};
    const float xni = 1.f / xnl[t];
#pragma unroll
    for (int g = 0; g < 8; ++g) lg[g] += simld[t][g] * xni * snr8[g];
    if (!FINAL) {
      *(float4*)lp = make_float4(lg[0], lg[1], lg[2], lg[3]);
      *(float4*)(lp + 4) = make_float4(lg[4], lg[5], lg[6], lg[7]);
    }
    float m = lg[0];
#pragma unroll
    for (int g = 1; g < 8; ++g) m = fmaxf(m, lg[g]);
    float sum = 0.f;
#pragma unroll
    for (int g = 0; g < 8; ++g) { lg[g] = __expf(lg[g] - m); sum += lg[g]; }
    float r = 1.f / sum;
    if (!FINAL) {
      unsigned short* wb = wgT + (size_t)b * 4096;
#pragma unroll
      for (int g = 0; g < 8; ++g) wb[g * 256 + c] = bfr(lg[g] * r);
#pragma unroll
      for (int g = 8; g < 16; ++g) wb[g * 256 + c] = 0;
    } else {
      float4* op = (float4*)(outw + ((size_t)b * 256 + c) * 8);
      op[0] = make_float4(lg[0] * r, lg[1] * r, lg[2] * r, lg[3] * r);
      op[1] = make_float4(lg[4] * r, lg[5] * r, lg[6] * r, lg[7] * r);
    }
  }
}

extern "C" void kernel_launch(void* const* d_in, const int* in_sizes, int n_in,
                              void* d_out, int out_size, void* d_ws, size_t ws_size,
                              hipStream_t stream) {
  const float* x = (const float*)d_in[0];
  const float* ga = (const float*)d_in[1];
  const float* conv_w = (const float*)d_in[2];
  const float* conv_b = (const float*)d_in[3];
  const float* lin_w = (const float*)d_in[4];
  const float* lin_b = (const float*)d_in[5];
  float* out = (float*)d_out;
  float* outx = out + 32768;  // x passthrough region

  float* ws = (float*)d_ws;
  float* pooledpart = ws;                               // 65536
  unsigned short* wbf = (unsigned short*)(ws + 65536);  // 16384 ushort
  float* logits = ws + 81920;                           // 32768
  unsigned short* wgT = (unsigned short*)(ws + 114688); // 65536 ushort (= 32768 f32)
  float* xnorm = ws + 147456;                           // 4096
  float* xnp = ws + 151552;                             // 262144
  float* spart2 = ws + 413696;                          // 8192
  float* simpart = ws + 421888;                         // 2097152

  k_wt<<<64, 256, 0, stream>>>(conv_w, wbf);
  k_prep<<<1024, 512, 0, stream>>>(x, wbf, conv_b, outx, xnp, pooledpart);
  k_logits<<<16, 256, 0, stream>>>(pooledpart, lin_w, lin_b, ga, logits, wgT);

  // iteration 1
  k_route<<<1024, 512, 0, stream>>>(x, wgT, spart2, simpart);
  k_upd<0><<<256, 256, 0, stream>>>(simpart, xnp, spart2, logits, xnorm, wgT, out);

  // iteration 2 (+ final softmax into d_out)
  k_route<<<1024, 512, 0, stream>>>(x, wgT, spart2, simpart);
  k_upd<1><<<256, 256, 0, stream>>>(simpart, xnp, spart2, logits, xnorm, wgT, out);
}

// Round 14
// 91.038 us; speedup vs baseline: 1.8007x; 1.0490x over previous
//
#include <hip/hip_runtime.h>

#define BB 16
#define CC 256
#define NN 4096
#define CN (CC*NN)
#define GG 8
#define EPSF 1e-8f
#define NT 64

typedef __attribute__((ext_vector_type(8))) short bf16x8;
typedef __attribute__((ext_vector_type(4))) float f32x4;
typedef __attribute__((ext_vector_type(2))) unsigned int uint32x2;

__device__ __forceinline__ unsigned short bfr(float f) {  // f32 -> bf16 RNE
  unsigned int u = __float_as_uint(f);
  return (unsigned short)((u + 0x7FFFu + ((u >> 16) & 1u)) >> 16);
}

// ---------------- prep: x passthrough + xnorm partials + MFMA conv/relu/pool ----------------
// + dumps the bf16 region-layout x tile to xbf_g (consumed by both k_route calls).
// grid: 16 b x 64 n-tiles(64). block 512 = 8 waves. LDS 32KB + pool.
__global__ __launch_bounds__(512) void k_prep(const float* __restrict__ x,
                                              const float* __restrict__ conv_w,
                                              const float* __restrict__ conv_b,
                                              float* __restrict__ xout,
                                              float* __restrict__ xnp,
                                              float* __restrict__ pooledpart,
                                              unsigned short* __restrict__ xbf_g) {
  const int b = blockIdx.x >> 6;
  const int chunk = blockIdx.x & 63;
  const int t = threadIdx.x;
  const int lane = t & 63, wv = t >> 6;
  __shared__ unsigned short xbf[16384];  // 32 KB: 32 regions [kk=c/32][nt=n/16], 32x16 each
  __shared__ float pool[8 * 16];

  const float* xb = x + (size_t)b * CN + chunk * NT;
  const int r0 = t >> 4, j = t & 15;
  float4 v[8];
  float sq[8];
#pragma unroll
  for (int k = 0; k < 8; ++k)
    v[k] = *(const float4*)(xb + (size_t)(k * 32 + r0) * NN + j * 4);
#pragma unroll
  for (int k = 0; k < 8; ++k) {
    ushort4 hh;
    hh.x = bfr(v[k].x); hh.y = bfr(v[k].y); hh.z = bfr(v[k].z); hh.w = bfr(v[k].w);
    *(ushort4*)&xbf[(k * 4 + (j >> 2)) * 512 + r0 * 16 + (j & 3) * 4] = hh;
    sq[k] = v[k].x * v[k].x + v[k].y * v[k].y + v[k].z * v[k].z + v[k].w * v[k].w;
  }
  float* xo = xout + (size_t)b * CN + chunk * NT;
#pragma unroll
  for (int k = 0; k < 8; ++k)
    *(float4*)(xo + (size_t)(k * 32 + r0) * NN + j * 4) = v[k];
#pragma unroll
  for (int k = 0; k < 8; ++k) {
    float s = sq[k];
    s += __shfl_xor(s, 1, 64); s += __shfl_xor(s, 2, 64);
    s += __shfl_xor(s, 4, 64); s += __shfl_xor(s, 8, 64);
    sq[k] = s;
  }
  if ((t & 15) == 0) {
    float* xp = xnp + ((size_t)b * 64 + chunk) * 256 + r0;
#pragma unroll
    for (int k = 0; k < 8; ++k) xp[k * 32] = sq[k];
  }
  __syncthreads();

  // dump bf16 tile to global (region-linear identity copy; overlaps conv below)
  {
    uint4* xgo4 = (uint4*)(xbf_g + (size_t)(b * 64 + chunk) * 16384);
    const uint4* xl4 = (const uint4*)xbf;
#pragma unroll
    for (int k = 0; k < 4; ++k) xgo4[k * 512 + t] = xl4[k * 512 + t];
  }

  // MFMA conv: D[d][n] = sum_c W[d][c] * X[c][n]; A-frags converted inline from conv_w f32
  const int dt = wv >> 1, h2 = wv & 1;
  const int g = lane >> 4, col = lane & 15;
  const int drow = dt * 16 + col;
  union AF { uint4 q; bf16x8 v; unsigned short u[8]; } a[8];
  const float* wrow = conv_w + (size_t)drow * 256;
#pragma unroll
  for (int kk = 0; kk < 8; ++kk) {
    float4 w0 = *(const float4*)(wrow + kk * 32 + g * 8);
    float4 w1 = *(const float4*)(wrow + kk * 32 + g * 8 + 4);
    a[kk].u[0] = bfr(w0.x); a[kk].u[1] = bfr(w0.y);
    a[kk].u[2] = bfr(w0.z); a[kk].u[3] = bfr(w0.w);
    a[kk].u[4] = bfr(w1.x); a[kk].u[5] = bfr(w1.y);
    a[kk].u[6] = bfr(w1.z); a[kk].u[7] = bfr(w1.w);
  }

  f32x4 acc0 = {0.f, 0.f, 0.f, 0.f}, acc1 = {0.f, 0.f, 0.f, 0.f};
  const unsigned int xbase = (unsigned int)(size_t)&xbf[0];
  const unsigned int lanoff = (unsigned int)(col * 2 + g * 256);
#pragma unroll
  for (int kk = 0; kk < 8; ++kk) {
    const unsigned int ra = xbase + (unsigned int)((kk * 4 + 2 * h2) * 1024) + lanoff;
    const unsigned int rb = ra + 1024;
    union BF { uint32x2 tr[2]; bf16x8 v; } b0, b1;
    asm volatile("ds_read_b64_tr_b16 %0, %1" : "=v"(b0.tr[0]) : "v"(ra));
    asm volatile("ds_read_b64_tr_b16 %0, %1" : "=v"(b0.tr[1]) : "v"(ra + 128));
    asm volatile("ds_read_b64_tr_b16 %0, %1" : "=v"(b1.tr[0]) : "v"(rb));
    asm volatile("ds_read_b64_tr_b16 %0, %1" : "=v"(b1.tr[1]) : "v"(rb + 128));
    asm volatile("s_waitcnt lgkmcnt(0)" ::: "memory");
    __builtin_amdgcn_sched_barrier(0);
    acc0 = __builtin_amdgcn_mfma_f32_16x16x32_bf16(a[kk].v, b0.v, acc0, 0, 0, 0);
    acc1 = __builtin_amdgcn_mfma_f32_16x16x32_bf16(a[kk].v, b1.v, acc1, 0, 0, 0);
  }
  const float4 bias = *(const float4*)(conv_b + dt * 16 + 4 * g);
  const float br[4] = {bias.x, bias.y, bias.z, bias.w};
  float hs[4];
#pragma unroll
  for (int r = 0; r < 4; ++r) {
    float hv = fmaxf(acc0[r] + br[r], 0.f) + fmaxf(acc1[r] + br[r], 0.f);
    hv += __shfl_xor(hv, 1, 64); hv += __shfl_xor(hv, 2, 64);
    hv += __shfl_xor(hv, 4, 64); hv += __shfl_xor(hv, 8, 64);
    hs[r] = hv;
  }
  if (col == 0) {
#pragma unroll
    for (int r = 0; r < 4; ++r) pool[wv * 16 + g * 4 + r] = hs[r];
  }
  __syncthreads();
  if (t < 64) {
    const int dtt = t >> 4, idx = t & 15;
    pooledpart[((size_t)b * 64 + chunk) * 64 + t] =
        pool[(dtt * 2) * 16 + idx] + pool[(dtt * 2 + 1) * 16 + idx];
  }
}

// ---------------- pooled-reduce + logits + softmax -> wgT (bf16 [16][256], rows 8-15 = 0) ---
__global__ __launch_bounds__(256) void k_logits(const float* __restrict__ pooledpart,
                                                const float* __restrict__ lin_w,
                                                const float* __restrict__ lin_b,
                                                const float* __restrict__ ga,
                                                float* __restrict__ logits,
                                                unsigned short* __restrict__ wgT) {
  const int b = blockIdx.x, t = threadIdx.x;
  __shared__ float ps2[4][64];
  __shared__ float ps[64];
  {
    const int d = t & 63, q = t >> 6;
    float s = 0.f;
#pragma unroll
    for (int k = 0; k < 16; ++k)
      s += pooledpart[((size_t)b * 64 + q * 16 + k) * 64 + d];
    ps2[q][d] = s;
  }
  __syncthreads();
  if (t < 64) ps[t] = (ps2[0][t] + ps2[1][t] + ps2[2][t] + ps2[3][t]) * (1.f / 4096.f);
  __syncthreads();
  const int c = t;
  float out[8];
#pragma unroll
  for (int g = 0; g < 8; ++g) {
    const float4* wr = (const float4*)(lin_w + ((size_t)c * 8 + g) * 64);
    float s = 0.f;
#pragma unroll
    for (int k4 = 0; k4 < 16; ++k4) {
      float4 wv = wr[k4];
      s += wv.x * ps[k4 * 4] + wv.y * ps[k4 * 4 + 1] + wv.z * ps[k4 * 4 + 2] +
           wv.w * ps[k4 * 4 + 3];
    }
    out[g] = s + lin_b[c * 8 + g] + logf(ga[((size_t)b * 256 + c) * 8 + g] + EPSF);
  }
  float* lp = logits + ((size_t)b * 256 + c) * 8;
  *(float4*)lp = make_float4(out[0], out[1], out[2], out[3]);
  *(float4*)(lp + 4) = make_float4(out[4], out[5], out[6], out[7]);
  float m = out[0];
#pragma unroll
  for (int g = 1; g < 8; ++g) m = fmaxf(m, out[g]);
  float sum = 0.f;
#pragma unroll
  for (int g = 0; g < 8; ++g) { out[g] = __expf(out[g] - m); sum += out[g]; }
  float r = 1.f / sum;
  unsigned short* wb = wgT + (size_t)b * 4096;
#pragma unroll
  for (int g = 0; g < 8; ++g) wb[g * 256 + c] = bfr(out[g] * r);
#pragma unroll
  for (int g = 8; g < 16; ++g) wb[g * 256 + c] = 0;
}

// ---------------- fused routing iteration, MFMA (stages pre-converted bf16 tile) ------------
// grid: 16 b x 64 n-tiles(64). block 512 = 8 waves. LDS ~34.3KB.
__global__ __launch_bounds__(512) void k_route(const unsigned short* __restrict__ xbf_g,
                                               const unsigned short* __restrict__ wgT,
                                               float* __restrict__ spart2,
                                               float* __restrict__ simpart) {
  const int b = blockIdx.x >> 6;
  const int chunk = blockIdx.x & 63;
  const int t = threadIdx.x;
  const int lane = t & 63, wv = t >> 6;
  const int col = lane & 15, grp = lane >> 4;
  __shared__ unsigned short xbf[16384];  // 32KB: identity copy of xbf_g block
  __shared__ unsigned short stb[1024];   // 2KB: 2 regions [kh=n/32], rows n(32) x cols g(16)
  __shared__ float spool[64];

  // stage pre-converted bf16 tile (identity layout, uint4 copy)
  {
    const uint4* xg = (const uint4*)(xbf_g + (size_t)(b * 64 + chunk) * 16384);
    uint4* xl = (uint4*)xbf;
#pragma unroll
    for (int k = 0; k < 4; ++k) xl[k * 512 + t] = xg[k * 512 + t];
  }
  __syncthreads();

  const unsigned int xbase = (unsigned int)(size_t)&xbf[0];
  const unsigned int sbase = (unsigned int)(size_t)&stb[0];
  const unsigned int lanoff = (unsigned int)(col * 2 + grp * 256);

  // ---- phase 1: waves 0-3, nt = wv ----
  if (wv < 4) {
    const int nt = wv;
    union AF { uint4 q; bf16x8 v; } a[8];
    const uint4* wq = (const uint4*)(wgT + (size_t)b * 4096);
#pragma unroll
    for (int kk = 0; kk < 8; ++kk) a[kk].q = wq[col * 32 + kk * 4 + grp];
    f32x4 acc = {0.f, 0.f, 0.f, 0.f};
#pragma unroll
    for (int kk = 0; kk < 8; ++kk) {
      const unsigned int ra = xbase + (unsigned int)((kk * 4 + nt) * 1024) + lanoff;
      union BF { uint32x2 tr[2]; bf16x8 v; } bf;
      asm volatile("ds_read_b64_tr_b16 %0, %1" : "=v"(bf.tr[0]) : "v"(ra));
      asm volatile("ds_read_b64_tr_b16 %0, %1" : "=v"(bf.tr[1]) : "v"(ra + 128));
      asm volatile("s_waitcnt lgkmcnt(0)" ::: "memory");
      __builtin_amdgcn_sched_barrier(0);
      acc = __builtin_amdgcn_mfma_f32_16x16x32_bf16(a[kk].v, bf.v, acc, 0, 0, 0);
    }
    {
      ushort4 sv4;
      sv4.x = bfr(acc[0]); sv4.y = bfr(acc[1]); sv4.z = bfr(acc[2]); sv4.w = bfr(acc[3]);
      *(ushort4*)&stb[(nt >> 1) * 512 + ((nt & 1) * 16 + col) * 16 + 4 * grp] = sv4;
      float s2[4];
#pragma unroll
      for (int r = 0; r < 4; ++r) {
        float vv = acc[r] * acc[r];
        vv += __shfl_xor(vv, 1, 64); vv += __shfl_xor(vv, 2, 64);
        vv += __shfl_xor(vv, 4, 64); vv += __shfl_xor(vv, 8, 64);
        s2[r] = vv;
      }
      if (col == 0) {
#pragma unroll
        for (int r = 0; r < 4; ++r) spool[nt * 16 + 4 * grp + r] = s2[r];
      }
    }
  }
  __syncthreads();
  if (t < 8)
    spart2[((size_t)b * 64 + chunk) * 8 + t] =
        spool[t] + spool[16 + t] + spool[32 + t] + spool[48 + t];

  // ---- phase 2: all 8 waves, mc = wv*2 + m2 ----
  float* sp = simpart + ((size_t)b * 64 + chunk) * 2048;
#pragma unroll
  for (int m2 = 0; m2 < 2; ++m2) {
    const int mc = wv * 2 + m2;
    const int kkA = mc >> 1;
    const int rowin = (mc & 1) * 16 + col;
    f32x4 acc = {0.f, 0.f, 0.f, 0.f};
#pragma unroll
    for (int kh = 0; kh < 2; ++kh) {
      union AF { uint4 q; bf16x8 v; } aa;
      aa.q = *(const uint4*)&xbf[(kkA * 4 + kh * 2 + (grp >> 1)) * 512 + rowin * 16 +
                                 (grp & 1) * 8];
      const unsigned int rb = sbase + (unsigned int)(kh * 1024) + lanoff;
      union BF { uint32x2 tr[2]; bf16x8 v; } bs;
      asm volatile("ds_read_b64_tr_b16 %0, %1" : "=v"(bs.tr[0]) : "v"(rb));
      asm volatile("ds_read_b64_tr_b16 %0, %1" : "=v"(bs.tr[1]) : "v"(rb + 128));
      asm volatile("s_waitcnt lgkmcnt(0)" ::: "memory");
      __builtin_amdgcn_sched_barrier(0);
      acc = __builtin_amdgcn_mfma_f32_16x16x32_bf16(aa.v, bs.v, acc, 0, 0, 0);
    }
    if (col < 8) {
#pragma unroll
      for (int r = 0; r < 4; ++r)
        sp[(size_t)(mc * 16 + 4 * grp + r) * 8 + col] = acc[r];
    }
  }
}

// ---------------- logits += sim/(xn*sn); !FINAL: softmax->wgT (+xnorm); FINAL: ->d_out ------
template <int FINAL>
__global__ __launch_bounds__(256) void k_upd(const float* __restrict__ simpart,
                                             const float* __restrict__ xnp,
                                             const float* __restrict__ spart2,
                                             float* __restrict__ logits,
                                             float* __restrict__ xnorm,
                                             unsigned short* __restrict__ wgT,
                                             float* __restrict__ outw) {
  const int b = blockIdx.x >> 4;
  const int c0 = (blockIdx.x & 15) * 16;
  const int t = threadIdx.x;
  __shared__ float simld[16][8];
  __shared__ float xnl[16];
  __shared__ float snr8[8];
  {
    const int pair = t >> 1, kh = t & 1;
    const int cl = pair >> 3, g = pair & 7;
    float sm = 0.f;
    const float* sp = simpart + (((size_t)b * 64 + kh * 32) * 256 + c0 + cl) * 8 + g;
#pragma unroll 8
    for (int k = 0; k < 32; ++k) sm += sp[(size_t)k * 2048];
    sm += __shfl_xor(sm, 1, 64);
    if (kh == 0) simld[cl][g] = sm;
  }
  {
    const int cl2 = t >> 4, kq = t & 15;
    if (!FINAL) {
      float p = 0.f;
#pragma unroll
      for (int jj = 0; jj < 4; ++jj)
        p += xnp[((size_t)b * 64 + kq + 16 * jj) * 256 + c0 + cl2];
      p += __shfl_xor(p, 1, 64); p += __shfl_xor(p, 2, 64);
      p += __shfl_xor(p, 4, 64); p += __shfl_xor(p, 8, 64);
      if (kq == 0) {
        float xn = fmaxf(sqrtf(p), EPSF);
        xnl[cl2] = xn;
        xnorm[b * 256 + c0 + cl2] = xn;
      }
    } else {
      if (kq == 0) xnl[cl2] = xnorm[b * 256 + c0 + cl2];
    }
  }
  if (t < 64) {
    const int g2 = t >> 3, kq = t & 7;
    float p = 0.f;
#pragma unroll
    for (int jj = 0; jj < 8; ++jj) p += spart2[((size_t)b * 64 + kq + 8 * jj) * 8 + g2];
    p += __shfl_xor(p, 1, 64); p += __shfl_xor(p, 2, 64); p += __shfl_xor(p, 4, 64);
    if (kq == 0) snr8[g2] = 1.f / fmaxf(sqrtf(p), EPSF);
  }
  __syncthreads();
  if (t < 16) {
    const int c = c0 + t;
    float* lp = logits + ((size_t)b * 256 + c) * 8;
    float4 l0 = *(const float4*)lp, l1 = *(const float4*)(lp + 4);
    float lg[8] = {l0.x, l0.y, l0.z, l0.w, l1.x, l1.y, l1.z, l1.w};
    const float xni = 1.f / xnl[t];
#pragma unroll
    for (int g = 0; g < 8; ++g) lg[g] += simld[t][g] * xni * snr8[g];
    if (!FINAL) {
      *(float4*)lp = make_float4(lg[0], lg[1], lg[2], lg[3]);
      *(float4*)(lp + 4) = make_float4(lg[4], lg[5], lg[6], lg[7]);
    }
    float m = lg[0];
#pragma unroll
    for (int g = 1; g < 8; ++g) m = fmaxf(m, lg[g]);
    float sum = 0.f;
#pragma unroll
    for (int g = 0; g < 8; ++g) { lg[g] = __expf(lg[g] - m); sum += lg[g]; }
    float r = 1.f / sum;
    if (!FINAL) {
      unsigned short* wb = wgT + (size_t)b * 4096;
#pragma unroll
      for (int g = 0; g < 8; ++g) wb[g * 256 + c] = bfr(lg[g] * r);
#pragma unroll
      for (int g = 8; g < 16; ++g) wb[g * 256 + c] = 0;
    } else {
      float4* op = (float4*)(outw + ((size_t)b * 256 + c) * 8);
      op[0] = make_float4(lg[0] * r, lg[1] * r, lg[2] * r, lg[3] * r);
      op[1] = make_float4(lg[4] * r, lg[5] * r, lg[6] * r, lg[7] * r);
    }
  }
}

extern "C" void kernel_launch(void* const* d_in, const int* in_sizes, int n_in,
                              void* d_out, int out_size, void* d_ws, size_t ws_size,
                              hipStream_t stream) {
  const float* x = (const float*)d_in[0];
  const float* ga = (const float*)d_in[1];
  const float* conv_w = (const float*)d_in[2];
  const float* conv_b = (const float*)d_in[3];
  const float* lin_w = (const float*)d_in[4];
  const float* lin_b = (const float*)d_in[5];
  float* out = (float*)d_out;
  float* outx = out + 32768;  // x passthrough region

  float* ws = (float*)d_ws;
  float* pooledpart = ws;                               // 65536
  float* logits = ws + 81920;                           // 32768
  unsigned short* wgT = (unsigned short*)(ws + 114688); // 65536 ushort
  float* xnorm = ws + 147456;                           // 4096
  float* xnp = ws + 151552;                             // 262144
  float* spart2 = ws + 413696;                          // 8192
  float* simpart = ws + 421888;                         // 2097152
  unsigned short* xbf_g = (unsigned short*)(ws + 2519040);  // 16.8M ushort (33.5MB)

  k_prep<<<1024, 512, 0, stream>>>(x, conv_w, conv_b, outx, xnp, pooledpart, xbf_g);
  k_logits<<<16, 256, 0, stream>>>(pooledpart, lin_w, lin_b, ga, logits, wgT);

  // iteration 1
  k_route<<<1024, 512, 0, stream>>>(xbf_g, wgT, spart2, simpart);
  k_upd<0><<<256, 256, 0, stream>>>(simpart, xnp, spart2, logits, xnorm, wgT, out);

  // iteration 2 (+ final softmax into d_out)
  k_route<<<1024, 512, 0, stream>>>(xbf_g, wgT, spart2, simpart);
  k_upd<1><<<256, 256, 0, stream>>>(simpart, xnp, spart2, logits, xnorm, wgT, out);
}

// Round 15
// 89.513 us; speedup vs baseline: 1.8313x; 1.0170x over previous
//
#include <hip/hip_runtime.h>

#define BB 16
#define CC 256
#define NN 4096
#define CN (CC*NN)
#define GG 8
#define EPSF 1e-8f
#define NT 64

typedef __attribute__((ext_vector_type(8))) short bf16x8;
typedef __attribute__((ext_vector_type(4))) float f32x4;
typedef __attribute__((ext_vector_type(2))) unsigned int uint32x2;

__device__ __forceinline__ unsigned short bfr(float f) {  // f32 -> bf16 RNE
  unsigned int u = __float_as_uint(f);
  return (unsigned short)((u + 0x7FFFu + ((u >> 16) & 1u)) >> 16);
}

// ---------------- prep: x passthrough + xnorm partials + MFMA conv/relu/pool ----------------
// + dumps the bf16 region-layout x tile to xbf_g (consumed by both k_route calls).
// grid: 16 b x 64 n-tiles(64). block 512 = 8 waves, (512,4): <=128 VGPR, 2 blocks/CU.
__global__ __launch_bounds__(512, 4) void k_prep(const float* __restrict__ x,
                                                 const float* __restrict__ conv_w,
                                                 const float* __restrict__ conv_b,
                                                 float* __restrict__ xout,
                                                 float* __restrict__ xnp,
                                                 float* __restrict__ pooledpart,
                                                 unsigned short* __restrict__ xbf_g) {
  const int b = blockIdx.x >> 6;
  const int chunk = blockIdx.x & 63;
  const int t = threadIdx.x;
  const int lane = t & 63, wv = t >> 6;
  __shared__ unsigned short xbf[16384];  // 32 KB: 32 regions [kk=c/32][nt=n/16], 32x16 each
  __shared__ float pool[8 * 16];

  // A-frags first: independent global loads (L2-hot), converted inline. Overlaps staging.
  const int dt = wv >> 1, h2 = wv & 1;
  const int g = lane >> 4, col = lane & 15;
  const int drow = dt * 16 + col;
  union AF { uint4 q; bf16x8 v; unsigned short u[8]; } a[8];
  {
    const float* wrow = conv_w + (size_t)drow * 256;
#pragma unroll
    for (int kk = 0; kk < 8; ++kk) {
      float4 w0 = *(const float4*)(wrow + kk * 32 + g * 8);
      float4 w1 = *(const float4*)(wrow + kk * 32 + g * 8 + 4);
      a[kk].u[0] = bfr(w0.x); a[kk].u[1] = bfr(w0.y);
      a[kk].u[2] = bfr(w0.z); a[kk].u[3] = bfr(w0.w);
      a[kk].u[4] = bfr(w1.x); a[kk].u[5] = bfr(w1.y);
      a[kk].u[6] = bfr(w1.z); a[kk].u[7] = bfr(w1.w);
    }
  }

  // stage x tile: rows c = k*32 + r0 (r0 = t>>4), float4-col j = t&15
  const float* xb = x + (size_t)b * CN + chunk * NT;
  const int r0 = t >> 4, j = t & 15;
  float4 v[8];
  float sq[8];
#pragma unroll
  for (int k = 0; k < 8; ++k)
    v[k] = *(const float4*)(xb + (size_t)(k * 32 + r0) * NN + j * 4);
#pragma unroll
  for (int k = 0; k < 8; ++k) {
    ushort4 hh;
    hh.x = bfr(v[k].x); hh.y = bfr(v[k].y); hh.z = bfr(v[k].z); hh.w = bfr(v[k].w);
    *(ushort4*)&xbf[(k * 4 + (j >> 2)) * 512 + r0 * 16 + (j & 3) * 4] = hh;
    sq[k] = v[k].x * v[k].x + v[k].y * v[k].y + v[k].z * v[k].z + v[k].w * v[k].w;
  }
  float* xo = xout + (size_t)b * CN + chunk * NT;
#pragma unroll
  for (int k = 0; k < 8; ++k)
    *(float4*)(xo + (size_t)(k * 32 + r0) * NN + j * 4) = v[k];
#pragma unroll
  for (int k = 0; k < 8; ++k) {
    float s = sq[k];
    s += __shfl_xor(s, 1, 64); s += __shfl_xor(s, 2, 64);
    s += __shfl_xor(s, 4, 64); s += __shfl_xor(s, 8, 64);
    sq[k] = s;
  }
  if ((t & 15) == 0) {
    float* xp = xnp + ((size_t)b * 64 + chunk) * 256 + r0;
#pragma unroll
    for (int k = 0; k < 8; ++k) xp[k * 32] = sq[k];
  }
  __syncthreads();

  // dump bf16 tile to global (region-linear identity copy; overlaps conv below)
  {
    uint4* xgo4 = (uint4*)(xbf_g + (size_t)(b * 64 + chunk) * 16384);
    const uint4* xl4 = (const uint4*)xbf;
#pragma unroll
    for (int k = 0; k < 4; ++k) xgo4[k * 512 + t] = xl4[k * 512 + t];
  }

  // MFMA conv: D[d][n] = sum_c W[d][c] * X[c][n]
  f32x4 acc0 = {0.f, 0.f, 0.f, 0.f}, acc1 = {0.f, 0.f, 0.f, 0.f};
  const unsigned int xbase = (unsigned int)(size_t)&xbf[0];
  const unsigned int lanoff = (unsigned int)(col * 2 + g * 256);
#pragma unroll
  for (int kk = 0; kk < 8; ++kk) {
    const unsigned int ra = xbase + (unsigned int)((kk * 4 + 2 * h2) * 1024) + lanoff;
    const unsigned int rb = ra + 1024;
    union BF { uint32x2 tr[2]; bf16x8 v; } b0, b1;
    asm volatile("ds_read_b64_tr_b16 %0, %1" : "=v"(b0.tr[0]) : "v"(ra));
    asm volatile("ds_read_b64_tr_b16 %0, %1" : "=v"(b0.tr[1]) : "v"(ra + 128));
    asm volatile("ds_read_b64_tr_b16 %0, %1" : "=v"(b1.tr[0]) : "v"(rb));
    asm volatile("ds_read_b64_tr_b16 %0, %1" : "=v"(b1.tr[1]) : "v"(rb + 128));
    asm volatile("s_waitcnt lgkmcnt(0)" ::: "memory");
    __builtin_amdgcn_sched_barrier(0);
    acc0 = __builtin_amdgcn_mfma_f32_16x16x32_bf16(a[kk].v, b0.v, acc0, 0, 0, 0);
    acc1 = __builtin_amdgcn_mfma_f32_16x16x32_bf16(a[kk].v, b1.v, acc1, 0, 0, 0);
  }
  const float4 bias = *(const float4*)(conv_b + dt * 16 + 4 * g);
  const float br[4] = {bias.x, bias.y, bias.z, bias.w};
  float hs[4];
#pragma unroll
  for (int r = 0; r < 4; ++r) {
    float hv = fmaxf(acc0[r] + br[r], 0.f) + fmaxf(acc1[r] + br[r], 0.f);
    hv += __shfl_xor(hv, 1, 64); hv += __shfl_xor(hv, 2, 64);
    hv += __shfl_xor(hv, 4, 64); hv += __shfl_xor(hv, 8, 64);
    hs[r] = hv;
  }
  if (col == 0) {
#pragma unroll
    for (int r = 0; r < 4; ++r) pool[wv * 16 + g * 4 + r] = hs[r];
  }
  __syncthreads();
  if (t < 64) {
    const int dtt = t >> 4, idx = t & 15;
    pooledpart[((size_t)b * 64 + chunk) * 64 + t] =
        pool[(dtt * 2) * 16 + idx] + pool[(dtt * 2 + 1) * 16 + idx];
  }
}

// ---------------- pooled-reduce + logits + softmax -> wgT (bf16 [16][256], rows 8-15 = 0) ---
__global__ __launch_bounds__(256) void k_logits(const float* __restrict__ pooledpart,
                                                const float* __restrict__ lin_w,
                                                const float* __restrict__ lin_b,
                                                const float* __restrict__ ga,
                                                float* __restrict__ logits,
                                                unsigned short* __restrict__ wgT) {
  const int b = blockIdx.x, t = threadIdx.x;
  __shared__ float ps2[4][64];
  __shared__ float ps[64];
  {
    const int d = t & 63, q = t >> 6;
    float s = 0.f;
#pragma unroll
    for (int k = 0; k < 16; ++k)
      s += pooledpart[((size_t)b * 64 + q * 16 + k) * 64 + d];
    ps2[q][d] = s;
  }
  __syncthreads();
  if (t < 64) ps[t] = (ps2[0][t] + ps2[1][t] + ps2[2][t] + ps2[3][t]) * (1.f / 4096.f);
  __syncthreads();
  const int c = t;
  float out[8];
#pragma unroll
  for (int g = 0; g < 8; ++g) {
    const float4* wr = (const float4*)(lin_w + ((size_t)c * 8 + g) * 64);
    float s = 0.f;
#pragma unroll
    for (int k4 = 0; k4 < 16; ++k4) {
      float4 wv = wr[k4];
      s += wv.x * ps[k4 * 4] + wv.y * ps[k4 * 4 + 1] + wv.z * ps[k4 * 4 + 2] +
           wv.w * ps[k4 * 4 + 3];
    }
    out[g] = s + lin_b[c * 8 + g] + logf(ga[((size_t)b * 256 + c) * 8 + g] + EPSF);
  }
  float* lp = logits + ((size_t)b * 256 + c) * 8;
  *(float4*)lp = make_float4(out[0], out[1], out[2], out[3]);
  *(float4*)(lp + 4) = make_float4(out[4], out[5], out[6], out[7]);
  float m = out[0];
#pragma unroll
  for (int g = 1; g < 8; ++g) m = fmaxf(m, out[g]);
  float sum = 0.f;
#pragma unroll
  for (int g = 0; g < 8; ++g) { out[g] = __expf(out[g] - m); sum += out[g]; }
  float r = 1.f / sum;
  unsigned short* wb = wgT + (size_t)b * 4096;
#pragma unroll
  for (int g = 0; g < 8; ++g) wb[g * 256 + c] = bfr(out[g] * r);
#pragma unroll
  for (int g = 8; g < 16; ++g) wb[g * 256 + c] = 0;
}

// ---------------- fused routing iteration, MFMA (stages pre-converted bf16 tile) ------------
// grid: 16 b x 64 n-tiles(64). block 512 = 8 waves. LDS ~34.3KB.
__global__ __launch_bounds__(512) void k_route(const unsigned short* __restrict__ xbf_g,
                                               const unsigned short* __restrict__ wgT,
                                               float* __restrict__ spart2,
                                               float* __restrict__ simpart) {
  const int b = blockIdx.x >> 6;
  const int chunk = blockIdx.x & 63;
  const int t = threadIdx.x;
  const int lane = t & 63, wv = t >> 6;
  const int col = lane & 15, grp = lane >> 4;
  __shared__ unsigned short xbf[16384];  // 32KB: identity copy of xbf_g block
  __shared__ unsigned short stb[1024];   // 2KB: 2 regions [kh=n/32], rows n(32) x cols g(16)
  __shared__ float spool[64];

  // stage pre-converted bf16 tile (identity layout, uint4 copy)
  {
    const uint4* xg = (const uint4*)(xbf_g + (size_t)(b * 64 + chunk) * 16384);
    uint4* xl = (uint4*)xbf;
#pragma unroll
    for (int k = 0; k < 4; ++k) xl[k * 512 + t] = xg[k * 512 + t];
  }
  __syncthreads();

  const unsigned int xbase = (unsigned int)(size_t)&xbf[0];
  const unsigned int sbase = (unsigned int)(size_t)&stb[0];
  const unsigned int lanoff = (unsigned int)(col * 2 + grp * 256);

  // ---- phase 1: waves 0-3, nt = wv ----
  if (wv < 4) {
    const int nt = wv;
    union AF { uint4 q; bf16x8 v; } a[8];
    const uint4* wq = (const uint4*)(wgT + (size_t)b * 4096);
#pragma unroll
    for (int kk = 0; kk < 8; ++kk) a[kk].q = wq[col * 32 + kk * 4 + grp];
    f32x4 acc = {0.f, 0.f, 0.f, 0.f};
#pragma unroll
    for (int kk = 0; kk < 8; ++kk) {
      const unsigned int ra = xbase + (unsigned int)((kk * 4 + nt) * 1024) + lanoff;
      union BF { uint32x2 tr[2]; bf16x8 v; } bf;
      asm volatile("ds_read_b64_tr_b16 %0, %1" : "=v"(bf.tr[0]) : "v"(ra));
      asm volatile("ds_read_b64_tr_b16 %0, %1" : "=v"(bf.tr[1]) : "v"(ra + 128));
      asm volatile("s_waitcnt lgkmcnt(0)" ::: "memory");
      __builtin_amdgcn_sched_barrier(0);
      acc = __builtin_amdgcn_mfma_f32_16x16x32_bf16(a[kk].v, bf.v, acc, 0, 0, 0);
    }
    {
      ushort4 sv4;
      sv4.x = bfr(acc[0]); sv4.y = bfr(acc[1]); sv4.z = bfr(acc[2]); sv4.w = bfr(acc[3]);
      *(ushort4*)&stb[(nt >> 1) * 512 + ((nt & 1) * 16 + col) * 16 + 4 * grp] = sv4;
      float s2[4];
#pragma unroll
      for (int r = 0; r < 4; ++r) {
        float vv = acc[r] * acc[r];
        vv += __shfl_xor(vv, 1, 64); vv += __shfl_xor(vv, 2, 64);
        vv += __shfl_xor(vv, 4, 64); vv += __shfl_xor(vv, 8, 64);
        s2[r] = vv;
      }
      if (col == 0) {
#pragma unroll
        for (int r = 0; r < 4; ++r) spool[nt * 16 + 4 * grp + r] = s2[r];
      }
    }
  }
  __syncthreads();
  if (t < 8)
    spart2[((size_t)b * 64 + chunk) * 8 + t] =
        spool[t] + spool[16 + t] + spool[32 + t] + spool[48 + t];

  // ---- phase 2: all 8 waves, mc = wv*2 + m2 ----
  float* sp = simpart + ((size_t)b * 64 + chunk) * 2048;
#pragma unroll
  for (int m2 = 0; m2 < 2; ++m2) {
    const int mc = wv * 2 + m2;
    const int kkA = mc >> 1;
    const int rowin = (mc & 1) * 16 + col;
    f32x4 acc = {0.f, 0.f, 0.f, 0.f};
#pragma unroll
    for (int kh = 0; kh < 2; ++kh) {
      union AF { uint4 q; bf16x8 v; } aa;
      aa.q = *(const uint4*)&xbf[(kkA * 4 + kh * 2 + (grp >> 1)) * 512 + rowin * 16 +
                                 (grp & 1) * 8];
      const unsigned int rb = sbase + (unsigned int)(kh * 1024) + lanoff;
      union BF { uint32x2 tr[2]; bf16x8 v; } bs;
      asm volatile("ds_read_b64_tr_b16 %0, %1" : "=v"(bs.tr[0]) : "v"(rb));
      asm volatile("ds_read_b64_tr_b16 %0, %1" : "=v"(bs.tr[1]) : "v"(rb + 128));
      asm volatile("s_waitcnt lgkmcnt(0)" ::: "memory");
      __builtin_amdgcn_sched_barrier(0);
      acc = __builtin_amdgcn_mfma_f32_16x16x32_bf16(aa.v, bs.v, acc, 0, 0, 0);
    }
    if (col < 8) {
#pragma unroll
      for (int r = 0; r < 4; ++r)
        sp[(size_t)(mc * 16 + 4 * grp + r) * 8 + col] = acc[r];
    }
  }
}

// ---------------- logits += sim/(xn*sn); !FINAL: softmax->wgT (+xnorm); FINAL: ->d_out ------
template <int FINAL>
__global__ __launch_bounds__(256) void k_upd(const float* __restrict__ simpart,
                                             const float* __restrict__ xnp,
                                             const float* __restrict__ spart2,
                                             float* __restrict__ logits,
                                             float* __restrict__ xnorm,
                                             unsigned short* __restrict__ wgT,
                                             float* __restrict__ outw) {
  const int b = blockIdx.x >> 4;
  const int c0 = (blockIdx.x & 15) * 16;
  const int t = threadIdx.x;
  __shared__ float simld[16][8];
  __shared__ float xnl[16];
  __shared__ float snr8[8];
  {
    const int pair = t >> 1, kh = t & 1;
    const int cl = pair >> 3, g = pair & 7;
    float sm = 0.f;
    const float* sp = simpart + (((size_t)b * 64 + kh * 32) * 256 + c0 + cl) * 8 + g;
#pragma unroll 8
    for (int k = 0; k < 32; ++k) sm += sp[(size_t)k * 2048];
    sm += __shfl_xor(sm, 1, 64);
    if (kh == 0) simld[cl][g] = sm;
  }
  {
    const int cl2 = t >> 4, kq = t & 15;
    if (!FINAL) {
      float p = 0.f;
#pragma unroll
      for (int jj = 0; jj < 4; ++jj)
        p += xnp[((size_t)b * 64 + kq + 16 * jj) * 256 + c0 + cl2];
      p += __shfl_xor(p, 1, 64); p += __shfl_xor(p, 2, 64);
      p += __shfl_xor(p, 4, 64); p += __shfl_xor(p, 8, 64);
      if (kq == 0) {
        float xn = fmaxf(sqrtf(p), EPSF);
        xnl[cl2] = xn;
        xnorm[b * 256 + c0 + cl2] = xn;
      }
    } else {
      if (kq == 0) xnl[cl2] = xnorm[b * 256 + c0 + cl2];
    }
  }
  if (t < 64) {
    const int g2 = t >> 3, kq = t & 7;
    float p = 0.f;
#pragma unroll
    for (int jj = 0; jj < 8; ++jj) p += spart2[((size_t)b * 64 + kq + 8 * jj) * 8 + g2];
    p += __shfl_xor(p, 1, 64); p += __shfl_xor(p, 2, 64); p += __shfl_xor(p, 4, 64);
    if (kq == 0) snr8[g2] = 1.f / fmaxf(sqrtf(p), EPSF);
  }
  __syncthreads();
  if (t < 16) {
    const int c = c0 + t;
    float* lp = logits + ((size_t)b * 256 + c) * 8;
    float4 l0 = *(const float4*)lp, l1 = *(const float4*)(lp + 4);
    float lg[8] = {l0.x, l0.y, l0.z, l0.w, l1.x, l1.y, l1.z, l1.w};
    const float xni = 1.f / xnl[t];
#pragma unroll
    for (int g = 0; g < 8; ++g) lg[g] += simld[t][g] * xni * snr8[g];
    if (!FINAL) {
      *(float4*)lp = make_float4(lg[0], lg[1], lg[2], lg[3]);
      *(float4*)(lp + 4) = make_float4(lg[4], lg[5], lg[6], lg[7]);
    }
    float m = lg[0];
#pragma unroll
    for (int g = 1; g < 8; ++g) m = fmaxf(m, lg[g]);
    float sum = 0.f;
#pragma unroll
    for (int g = 0; g < 8; ++g) { lg[g] = __expf(lg[g] - m); sum += lg[g]; }
    float r = 1.f / sum;
    if (!FINAL) {
      unsigned short* wb = wgT + (size_t)b * 4096;
#pragma unroll
      for (int g = 0; g < 8; ++g) wb[g * 256 + c] = bfr(lg[g] * r);
#pragma unroll
      for (int g = 8; g < 16; ++g) wb[g * 256 + c] = 0;
    } else {
      float4* op = (float4*)(outw + ((size_t)b * 256 + c) * 8);
      op[0] = make_float4(lg[0] * r, lg[1] * r, lg[2] * r, lg[3] * r);
      op[1] = make_float4(lg[4] * r, lg[5] * r, lg[6] * r, lg[7] * r);
    }
  }
}

extern "C" void kernel_launch(void* const* d_in, const int* in_sizes, int n_in,
                              void* d_out, int out_size, void* d_ws, size_t ws_size,
                              hipStream_t stream) {
  const float* x = (const float*)d_in[0];
  const float* ga = (const float*)d_in[1];
  const float* conv_w = (const float*)d_in[2];
  const float* conv_b = (const float*)d_in[3];
  const float* lin_w = (const float*)d_in[4];
  const float* lin_b = (const float*)d_in[5];
  float* out = (float*)d_out;
  float* outx = out + 32768;  // x passthrough region

  float* ws = (float*)d_ws;
  float* pooledpart = ws;                               // 65536
  float* logits = ws + 81920;                           // 32768
  unsigned short* wgT = (unsigned short*)(ws + 114688); // 65536 ushort
  float* xnorm = ws + 147456;                           // 4096
  float* xnp = ws + 151552;                             // 262144
  float* spart2 = ws + 413696;                          // 8192
  float* simpart = ws + 421888;                         // 2097152
  unsigned short* xbf_g = (unsigned short*)(ws + 2519040);  // 16.8M ushort (33.5MB)

  k_prep<<<1024, 512, 0, stream>>>(x, conv_w, conv_b, outx, xnp, pooledpart, xbf_g);
  k_logits<<<16, 256, 0, stream>>>(pooledpart, lin_w, lin_b, ga, logits, wgT);

  // iteration 1
  k_route<<<1024, 512, 0, stream>>>(xbf_g, wgT, spart2, simpart);
  k_upd<0><<<256, 256, 0, stream>>>(simpart, xnp, spart2, logits, xnorm, wgT, out);

  // iteration 2 (+ final softmax into d_out)
  k_route<<<1024, 512, 0, stream>>>(xbf_g, wgT, spart2, simpart);
  k_upd<1><<<256, 256, 0, stream>>>(simpart, xnp, spart2, logits, xnorm, wgT, out);
}